// Round 1
// baseline (389.680 us; speedup 1.0000x reference)
//
#include <hip/hip_runtime.h>
#include <math.h>

#define B_   128
#define N1_  128
#define N2_  384
#define N_   512
#define E_   1024
#define DIN  64
#define DFC  128

// workspace layout (floats)
#define ACC_TOP  0
#define ACC_BOT  128
#define POOL_OFF 256                          // B*64 = 8192
#define RNI_OFF  (POOL_OFF + B_*DIN)          // 8448:  B*N1 reciprocal rownorms
#define BI_OFF   (RNI_OFF + B_*N1_)           // 24832: B*N1 argmax ints
#define CNI_OFF  (BI_OFF + B_*N1_)            // 41216: B*N2 col ssq -> reciprocal colnorms (in-place)

// ---------------- init ----------------
// grid 192, block 256  (zero acc+pool 8448 and col-ssq 49152)
__global__ void k_init(float* ws, float* out) {
    int idx = blockIdx.x * 256 + threadIdx.x;
    if (idx < 256 + B_ * DIN) ws[idx] = 0.f;
    if (idx < B_ * N2_) ws[CNI_OFF + idx] = 0.f;
    if (idx < 4) out[128 + idx] = 0.f;
}

// ---------------- front: pool (y<8) | att single pass: rownorm+argmax+col-ssq (y in 8..39) ----
// grid (B, 40), block 256
__global__ void k_front(const float* __restrict__ c_hs, const float* __restrict__ c_valid,
                        const float* __restrict__ att, float* __restrict__ ws) {
    __shared__ float4 sred4[256];
    int b = blockIdx.x, y = blockIdx.y, t = threadIdx.x;
    if (y < 8) {
        // masked mean-pool partial: 64 rows
        int chunk = y * 64;
        int d4 = t & 15, rl = t >> 4;
        const float4* X4 = (const float4*)(c_hs + (size_t)b * N_ * DIN);
        const float* V = c_valid + (size_t)b * N_;
        float4 acc = {0.f, 0.f, 0.f, 0.f};
        #pragma unroll
        for (int r = chunk + rl; r < chunk + 64; r += 16) {
            float4 x = X4[r * 16 + d4];
            float v = V[r];
            acc.x += x.x * v; acc.y += x.y * v; acc.z += x.z * v; acc.w += x.w * v;
        }
        sred4[t] = acc; __syncthreads();
        for (int off = 128; off >= 16; off >>= 1) {
            if (t < off) {
                float4 o = sred4[t + off];
                sred4[t].x += o.x; sred4[t].y += o.y; sred4[t].z += o.z; sred4[t].w += o.w;
            }
            __syncthreads();
        }
        if (t < 16) {
            float4 s = sred4[t];
            float* p = ws + POOL_OFF + b * DIN + t * 4;
            atomicAdd(&p[0], s.x); atomicAdd(&p[1], s.y);
            atomicAdd(&p[2], s.z); atomicAdd(&p[3], s.w);
        }
        return;
    }
    // att pass: 4 rows (one per wave), fused row-ssq + argmax + col-ssq partials
    float* colacc = (float*)sred4;               // 384 floats
    for (int c = t; c < N2_; c += 256) colacc[c] = 0.f;
    __syncthreads();
    int wv = t >> 6, ln = t & 63;
    int r = (y - 8) * 4 + wv;
    const float* row = att + ((size_t)b * N1_ + r) * N2_;
    float vv[6];
    float ssq = 0.f, best = -1e30f; int bidx = 0;
    #pragma unroll
    for (int q = 0; q < 6; ++q) {
        float v = row[ln + 64 * q];
        vv[q] = v;
        ssq += v * v;
        if (v > best) { best = v; bidx = ln + 64 * q; }   // ascending: > keeps first
    }
    #pragma unroll
    for (int q = 0; q < 6; ++q) atomicAdd(&colacc[ln + 64 * q], vv[q] * vv[q]);
    for (int off = 32; off > 0; off >>= 1) {
        ssq += __shfl_xor(ssq, off, 64);
        float ov = __shfl_xor(best, off, 64);
        int oi = __shfl_xor(bidx, off, 64);
        if (ov > best || (ov == best && oi < bidx)) { best = ov; bidx = oi; }
    }
    if (ln == 0) {
        ws[RNI_OFF + b * N1_ + r] = 1.f / fmaxf(sqrtf(ssq), 1e-12f);
        ((int*)ws)[BI_OFF + b * N1_ + r] = bidx;
    }
    __syncthreads();
    for (int c = t; c < N2_; c += 256)
        atomicAdd(&ws[CNI_OFF + b * N2_ + c], colacc[c]);
}

// ---------------- fin: col ssq -> reciprocal norm (in place) ----------------
// grid (B), block 384
__global__ void k_fin(float* __restrict__ ws) {
    int b = blockIdx.x, t = threadIdx.x;
    float v = ws[CNI_OFF + b * N2_ + t];
    ws[CNI_OFF + b * N2_ + t] = 1.f / fmaxf(sqrtf(v), 1e-12f);
}

// ---------------- fused mask scan: 8 rows/block, deep MLP, no LDS for type A ----------------
// grid (64, B), block 256
#define EWS 132
__global__ __launch_bounds__(256, 4)
void k_scan(const float* __restrict__ att, const float* __restrict__ mapping,
            const float* __restrict__ samelb, float* __restrict__ ws) {
    __shared__ float ew[8 * EWS];
    __shared__ float rt[4], rb[4];
    int b = blockIdx.y, t = threadIdx.x;
    float top = 0.f, bot = 0.f;
    int r = t >> 5, c4 = t & 31;                  // r: 0..7 row-in-tile, c4: float4 col
    if (blockIdx.x < 16) {
        // type A: mask rows [0,128) in 8-row tiles. cols<128: count; cols>=128: exp(-att*cninv)
        int i0 = blockIdx.x * 8;
        const float4* m4 = (const float4*)(mapping + ((size_t)b * N_ + i0) * N_);
        const float4* s4 = (const float4*)(samelb + ((size_t)b * N_ + i0) * N_);
        const float4* a4 = (const float4*)(att + ((size_t)b * N1_ + i0) * N2_);
        const float4* cn4 = (const float4*)(ws + CNI_OFF + (size_t)b * N2_);
        // all loads independent — issue everything, then compute
        float4 md = m4[r * 128 + c4];
        float4 sd = s4[r * 128 + c4];
        float4 av[3], mv[3], sv[3], cn[3];
        #pragma unroll
        for (int k = 0; k < 3; ++k) {
            int c = c4 + 32 * k;
            av[k] = a4[r * 96 + c];
            mv[k] = m4[r * 128 + 32 + c];
            sv[k] = s4[r * 128 + 32 + c];
            cn[k] = cn4[c];
        }
        top = md.x + md.y + md.z + md.w;
        bot = sd.x + sd.y + sd.z + sd.w;
        #pragma unroll
        for (int k = 0; k < 3; ++k) {
            float e0 = __expf(-av[k].x * cn[k].x);
            float e1 = __expf(-av[k].y * cn[k].y);
            float e2 = __expf(-av[k].z * cn[k].z);
            float e3 = __expf(-av[k].w * cn[k].w);
            top += mv[k].x * e0 + mv[k].y * e1 + mv[k].z * e2 + mv[k].w * e3;
            bot += sv[k].x * e0 + sv[k].y * e1 + sv[k].z * e2 + sv[k].w * e3;
        }
    } else {
        // type B: mask rows [128,512) in 8-row tiles; ew[rr][j] = exp(-att[j][cr0+rr]*rinv[j])
        int tb = blockIdx.x - 16;                 // 0..47
        int cr0 = tb * 8;
        const float4* a4 = (const float4*)(att + (size_t)b * N1_ * N2_);
        {
            int j = t >> 1, q = t & 1;
            float4 a = a4[j * 96 + tb * 2 + q];
            float rv = ws[RNI_OFF + b * N1_ + j];
            ew[(4 * q + 0) * EWS + j] = __expf(-a.x * rv);
            ew[(4 * q + 1) * EWS + j] = __expf(-a.y * rv);
            ew[(4 * q + 2) * EWS + j] = __expf(-a.z * rv);
            ew[(4 * q + 3) * EWS + j] = __expf(-a.w * rv);
        }
        const float4* m4 = (const float4*)(mapping + ((size_t)b * N_ + N1_ + cr0) * N_);
        const float4* s4 = (const float4*)(samelb + ((size_t)b * N_ + N1_ + cr0) * N_);
        // independent mask loads issued before the ew barrier
        float4 mL = m4[r * 128 + c4];
        float4 sL = s4[r * 128 + c4];
        float4 mR[3], sR[3];
        #pragma unroll
        for (int k = 0; k < 3; ++k) {
            int c = c4 + 32 * k;
            mR[k] = m4[r * 128 + 32 + c];
            sR[k] = s4[r * 128 + 32 + c];
        }
        __syncthreads();
        float4 w = *(const float4*)&ew[r * EWS + c4 * 4];
        top = mL.x * w.x + mL.y * w.y + mL.z * w.z + mL.w * w.w;
        bot = sL.x * w.x + sL.y * w.y + sL.z * w.z + sL.w * w.w;
        #pragma unroll
        for (int k = 0; k < 3; ++k) {
            top += mR[k].x + mR[k].y + mR[k].z + mR[k].w;
            bot += sR[k].x + sR[k].y + sR[k].z + sR[k].w;
        }
    }
    for (int off = 32; off > 0; off >>= 1) {
        top += __shfl_down(top, off, 64);
        bot += __shfl_down(bot, off, 64);
    }
    int wv = t >> 6, ln = t & 63;
    if (ln == 0) { rt[wv] = top; rb[wv] = bot; }
    __syncthreads();
    if (t == 0) {
        atomicAdd(&ws[ACC_TOP + b], rt[0] + rt[1] + rt[2] + rt[3]);
        atomicAdd(&ws[ACC_BOT + b], rb[0] + rb[1] + rb[2] + rb[3]);
    }
}

// ---------------- back: kabsch+pair+finalize (y==0) | scores MLP (y==1) ----------------
__device__ inline float bred(float* s2, float v, int t) {
    for (int off = 32; off > 0; off >>= 1) v += __shfl_down(v, off, 64);
    if ((t & 63) == 0) s2[t >> 6] = v;
    __syncthreads();
    float r = s2[0] + s2[1];
    __syncthreads();
    return r;
}

// grid (B, 2), block 128
__global__ void k_back(const float* __restrict__ coords, const float* __restrict__ upd,
                       const float* __restrict__ nm, const int* __restrict__ ei,
                       const float* __restrict__ W0, const float* __restrict__ b0,
                       const float* __restrict__ W1, const float* __restrict__ b1,
                       const float* __restrict__ W2, const float* __restrict__ b2,
                       const float* __restrict__ W3, const float* __restrict__ b3,
                       const float* __restrict__ ws, float* __restrict__ out) {
    __shared__ float sh[2 * DFC];
    int b = blockIdx.x, t = threadIdx.x;
    if (blockIdx.y == 1) {
        // ---- scores MLP ----
        float* pool = sh;           // 64
        float* h    = sh + 64;      // 128
        __shared__ float part[DFC];
        if (t < DIN) pool[t] = ws[POOL_OFF + b * DIN + t] * (1.0f / 128.0f);
        __syncthreads();
        float a = b0[t];
        #pragma unroll
        for (int i = 0; i < DIN; ++i) a += pool[i] * W0[i * DFC + t];
        float hv = fmaxf(a, 0.f);
        __syncthreads(); h[t] = hv; __syncthreads();
        a = b1[t];
        #pragma unroll
        for (int i = 0; i < DFC; ++i) a += h[i] * W1[i * DFC + t];
        hv = fmaxf(a, 0.f);
        __syncthreads(); h[t] = hv; __syncthreads();
        a = b2[t];
        #pragma unroll
        for (int i = 0; i < DFC; ++i) a += h[i] * W2[i * DFC + t];
        part[t] = fmaxf(a, 0.f) * W3[t];
        __syncthreads();
        for (int off = 64; off > 0; off >>= 1) { if (t < off) part[t] += part[t + off]; __syncthreads(); }
        if (t == 0) out[b] = 1.f / (1.f + expf(-(part[0] + b3[0])));
        return;
    }
    // ---- Kabsch ----
    float* s2 = sh;
    __shared__ float Rsh[9], Tsh[3];
    int bidx = ((const int*)ws)[BI_OFF + b * N1_ + t];
    float P[3], Q[3];
    const float* up = upd + ((size_t)b * N_ + t) * 3;
    P[0] = up[0]; P[1] = up[1]; P[2] = up[2];
    const float* qp = coords + ((size_t)b * N_ + N1_ + bidx) * 3;
    Q[0] = qp[0]; Q[1] = qp[1]; Q[2] = qp[2];
    float Pm[3], Qm[3];
    for (int a = 0; a < 3; ++a) Pm[a] = bred(s2, P[a], t) * (1.f / 128.f);
    for (int a = 0; a < 3; ++a) Qm[a] = bred(s2, Q[a], t) * (1.f / 128.f);
    float H[9];
    for (int a = 0; a < 3; ++a)
        for (int c = 0; c < 3; ++c)
            H[a * 3 + c] = bred(s2, (P[a] - Pm[a]) * (Q[c] - Qm[c]), t) * (1.f / 8.f);
    if (t == 0) {
        double Hd[3][3];
        for (int a = 0; a < 3; ++a) for (int c = 0; c < 3; ++c) Hd[a][c] = (double)H[a * 3 + c];
        double A[3][3], V[3][3] = {{1,0,0},{0,1,0},{0,0,1}};
        for (int i = 0; i < 3; ++i)
            for (int j = 0; j < 3; ++j) {
                double z = 0; for (int c = 0; c < 3; ++c) z += Hd[c][i] * Hd[c][j];
                A[i][j] = z;
            }
        for (int sweep = 0; sweep < 8; ++sweep) {
            const int PQ[3][2] = {{0,1},{0,2},{1,2}};
            for (int r = 0; r < 3; ++r) {
                int p = PQ[r][0], q = PQ[r][1];
                double apq = A[p][q];
                if (fabs(apq) < 1e-300) continue;
                double tau = (A[q][q] - A[p][p]) / (2.0 * apq);
                double tt = (tau >= 0 ? 1.0 : -1.0) / (fabs(tau) + sqrt(1.0 + tau * tau));
                double c = 1.0 / sqrt(1.0 + tt * tt), s = tt * c;
                for (int k = 0; k < 3; ++k) { double akp = A[k][p], akq = A[k][q]; A[k][p] = c * akp - s * akq; A[k][q] = s * akp + c * akq; }
                for (int k = 0; k < 3; ++k) { double apk = A[p][k], aqk = A[q][k]; A[p][k] = c * apk - s * aqk; A[q][k] = s * apk + c * aqk; }
                for (int k = 0; k < 3; ++k) { double vkp = V[k][p], vkq = V[k][q]; V[k][p] = c * vkp - s * vkq; V[k][q] = s * vkp + c * vkq; }
            }
        }
        double lam[3] = {A[0][0], A[1][1], A[2][2]};
        int id[3] = {0, 1, 2};
        if (lam[id[0]] < lam[id[1]]) { int x = id[0]; id[0] = id[1]; id[1] = x; }
        if (lam[id[0]] < lam[id[2]]) { int x = id[0]; id[0] = id[2]; id[2] = x; }
        if (lam[id[1]] < lam[id[2]]) { int x = id[1]; id[1] = id[2]; id[2] = x; }
        double u[3][3], v[3][3], sv[3];
        for (int i = 0; i < 3; ++i) {
            for (int k = 0; k < 3; ++k) v[i][k] = V[k][id[i]];
            double uv[3];
            for (int c = 0; c < 3; ++c) uv[c] = Hd[c][0] * v[i][0] + Hd[c][1] * v[i][1] + Hd[c][2] * v[i][2];
            double n = sqrt(uv[0] * uv[0] + uv[1] * uv[1] + uv[2] * uv[2]);
            sv[i] = n;
            if (n > 1e-150) { u[i][0] = uv[0] / n; u[i][1] = uv[1] / n; u[i][2] = uv[2] / n; }
            else { u[i][0] = u[i][1] = u[i][2] = 0.0; }
        }
        if (sv[2] < 1e-12 * fmax(sv[0], 1e-300)) {
            u[2][0] = u[0][1] * u[1][2] - u[0][2] * u[1][1];
            u[2][1] = u[0][2] * u[1][0] - u[0][0] * u[1][2];
            u[2][2] = u[0][0] * u[1][1] - u[0][1] * u[1][0];
        }
        double det = Hd[0][0] * (Hd[1][1] * Hd[2][2] - Hd[1][2] * Hd[2][1])
                   - Hd[0][1] * (Hd[1][0] * Hd[2][2] - Hd[1][2] * Hd[2][0])
                   + Hd[0][2] * (Hd[1][0] * Hd[2][1] - Hd[1][1] * Hd[2][0]);
        double dsg = (det > 0.0) ? 1.0 : ((det < 0.0) ? -1.0 : 0.0);
        for (int a = 0; a < 3; ++a)
            for (int c = 0; c < 3; ++c)
                Rsh[a * 3 + c] = (float)(u[0][a] * v[0][c] + u[1][a] * v[1][c] + dsg * u[2][a] * v[2][c]);
        for (int a = 0; a < 3; ++a)
            Tsh[a] = Qm[a] - (Rsh[a * 3] * Pm[0] + Rsh[a * 3 + 1] * Pm[1] + Rsh[a * 3 + 2] * Pm[2]);
    }
    __syncthreads();
    float Pp[3];
    for (int a = 0; a < 3; ++a)
        Pp[a] = Rsh[a * 3] * P[0] + Rsh[a * 3 + 1] * P[1] + Rsh[a * 3 + 2] * P[2] + Tsh[a];
    float mk = (nm[b * N1_ + t] > 0.5f) ? 1.f : 0.f;
    float dx = Pp[0] - Q[0], dy = Pp[1] - Q[1], dz = Pp[2] - Q[2];
    float rsum = bred(s2, mk * (dx * dx + dy * dy + dz * dz), t);
    float msum = bred(s2, mk, t);
    float Ppm[3];
    for (int a = 0; a < 3; ++a) Ppm[a] = bred(s2, Pp[a], t) * (1.f / 128.f);
    if (t == 0) {
        float cnt = fmaxf(msum * 3.f, 1.f);
        atomicAdd(&out[129], (rsum / cnt) * (1.f / 128.f));
        float cen = 0.f;
        for (int a = 0; a < 3; ++a) { float d2 = Ppm[a] - Qm[a]; cen += d2 * d2; }
        atomicAdd(&out[131], (cen / 3.f) * (1.f / 128.f));
    }
    // ---- fused pairdst ----
    const float* C = coords + (size_t)b * N_ * 3;
    const float* U = upd + (size_t)b * N_ * 3;
    const int* e = ei + (size_t)b * E_ * 2;
    float acc = 0.f;
    for (int idx = t; idx < E_; idx += 128) {
        int a0 = e[idx * 2], a1 = e[idx * 2 + 1];
        float ex = C[a0 * 3] - C[a1 * 3], ey = C[a0 * 3 + 1] - C[a1 * 3 + 1], ez = C[a0 * 3 + 2] - C[a1 * 3 + 2];
        float d0 = sqrtf(ex * ex + ey * ey + ez * ez + 1e-12f);
        ex = U[a0 * 3] - U[a1 * 3]; ey = U[a0 * 3 + 1] - U[a1 * 3 + 1]; ez = U[a0 * 3 + 2] - U[a1 * 3 + 2];
        float d1 = sqrtf(ex * ex + ey * ey + ez * ez + 1e-12f);
        acc += d1 - d0;
    }
    float psum = bred(s2, acc, t);
    if (t == 0) atomicAdd(&out[130], fabsf(psum) * (1.f / 128.f));
    // ---- attn_loss finalize ----
    if (b == 0) {
        float top = ws[ACC_TOP + t], bot = ws[ACC_BOT + t];
        float v = top / (bot - top + 1.0f);
        float s = bred(s2, v, t);
        if (t == 0) out[128] = s * (1.0f / 128.0f);
    }
}

extern "C" void kernel_launch(void* const* d_in, const int* in_sizes, int n_in,
                              void* d_out, int out_size, void* d_ws, size_t ws_size,
                              hipStream_t stream) {
    const float* c_hs      = (const float*)d_in[0];
    const float* attention = (const float*)d_in[1];
    const float* coords    = (const float*)d_in[2];
    const float* upd       = (const float*)d_in[3];
    const float* c_valid   = (const float*)d_in[4];
    const float* nm        = (const float*)d_in[5];
    const float* mapping   = (const float*)d_in[6];
    const float* samelb    = (const float*)d_in[7];
    const int*   ei        = (const int*)d_in[8];
    const float* W0 = (const float*)d_in[9],  *b0 = (const float*)d_in[10];
    const float* W1 = (const float*)d_in[11], *b1 = (const float*)d_in[12];
    const float* W2 = (const float*)d_in[13], *b2 = (const float*)d_in[14];
    const float* W3 = (const float*)d_in[15], *b3 = (const float*)d_in[16];
    float* out = (float*)d_out;
    float* ws  = (float*)d_ws;

    hipLaunchKernelGGL(k_init,  dim3(192),     dim3(256), 0, stream, ws, out);
    hipLaunchKernelGGL(k_front, dim3(B_, 40),  dim3(256), 0, stream, c_hs, c_valid, attention, ws);
    hipLaunchKernelGGL(k_fin,   dim3(B_),      dim3(N2_), 0, stream, ws);
    hipLaunchKernelGGL(k_scan,  dim3(64, B_),  dim3(256), 0, stream, attention, mapping, samelb, ws);
    hipLaunchKernelGGL(k_back,  dim3(B_, 2),   dim3(128), 0, stream, coords, upd, nm, ei,
                       W0, b0, W1, b1, W2, b2, W3, b3, ws, out);
}

// Round 3
// 364.202 us; speedup vs baseline: 1.0700x; 1.0700x over previous
//
#include <hip/hip_runtime.h>
#include <math.h>

#define B_   128
#define N1_  128
#define N2_  384
#define N_   512
#define E_   1024
#define DIN  64
#define DFC  128

// workspace layout (floats)
#define ACC_TOP  0
#define ACC_BOT  128
#define POOL_OFF 256                          // B*64 = 8192
#define RNI_OFF  (POOL_OFF + B_*DIN)          // 8448:  B*N1 reciprocal rownorms
#define BI_OFF   (RNI_OFF + B_*N1_)           // 24832: B*N1 argmax ints
#define CNI_OFF  (BI_OFF + B_*N1_)            // 41216: B*N2 col ssq -> reciprocal colnorms (in-place)

// nontemporal float4 load: __builtin_nontemporal_load needs a native vector type,
// not HIP_vector_type — go through a clang ext_vector alias (same layout).
typedef float f4v __attribute__((ext_vector_type(4)));
__device__ __forceinline__ float4 ntl4(const float4* p) {
    f4v v = __builtin_nontemporal_load((const f4v*)p);
    float4 r; r.x = v.x; r.y = v.y; r.z = v.z; r.w = v.w;
    return r;
}

// ---------------- init ----------------
// grid 192, block 256  (zero acc+pool 8448 and col-ssq 49152)
__global__ void k_init(float* ws, float* out) {
    int idx = blockIdx.x * 256 + threadIdx.x;
    if (idx < 256 + B_ * DIN) ws[idx] = 0.f;
    if (idx < B_ * N2_) ws[CNI_OFF + idx] = 0.f;
    if (idx < 4) out[128 + idx] = 0.f;
}

// ---------------- front: pool (y<8) | att single pass: rownorm+argmax+col-ssq (y in 8..39) ----
// grid (B, 40), block 256
__global__ void k_front(const float* __restrict__ c_hs, const float* __restrict__ c_valid,
                        const float* __restrict__ att, float* __restrict__ ws) {
    __shared__ float4 sred4[256];
    int b = blockIdx.x, y = blockIdx.y, t = threadIdx.x;
    if (y < 8) {
        // masked mean-pool partial: 64 rows  (c_hs is single-use -> nontemporal)
        int chunk = y * 64;
        int d4 = t & 15, rl = t >> 4;
        const float4* X4 = (const float4*)(c_hs + (size_t)b * N_ * DIN);
        const float* V = c_valid + (size_t)b * N_;
        float4 acc = {0.f, 0.f, 0.f, 0.f};
        #pragma unroll
        for (int r = chunk + rl; r < chunk + 64; r += 16) {
            float4 x = ntl4(&X4[r * 16 + d4]);
            float v = V[r];
            acc.x += x.x * v; acc.y += x.y * v; acc.z += x.z * v; acc.w += x.w * v;
        }
        sred4[t] = acc; __syncthreads();
        for (int off = 128; off >= 16; off >>= 1) {
            if (t < off) {
                float4 o = sred4[t + off];
                sred4[t].x += o.x; sred4[t].y += o.y; sred4[t].z += o.z; sred4[t].w += o.w;
            }
            __syncthreads();
        }
        if (t < 16) {
            float4 s = sred4[t];
            float* p = ws + POOL_OFF + b * DIN + t * 4;
            atomicAdd(&p[0], s.x); atomicAdd(&p[1], s.y);
            atomicAdd(&p[2], s.z); atomicAdd(&p[3], s.w);
        }
        return;
    }
    // att pass: 4 rows (one per wave), fused row-ssq + argmax + col-ssq partials
    float* colacc = (float*)sred4;               // 384 floats
    for (int c = t; c < N2_; c += 256) colacc[c] = 0.f;
    __syncthreads();
    int wv = t >> 6, ln = t & 63;
    int r = (y - 8) * 4 + wv;
    const float* row = att + ((size_t)b * N1_ + r) * N2_;
    float vv[6];
    float ssq = 0.f, best = -1e30f; int bidx = 0;
    #pragma unroll
    for (int q = 0; q < 6; ++q) {
        float v = row[ln + 64 * q];
        vv[q] = v;
        ssq += v * v;
        if (v > best) { best = v; bidx = ln + 64 * q; }   // ascending: > keeps first
    }
    #pragma unroll
    for (int q = 0; q < 6; ++q) atomicAdd(&colacc[ln + 64 * q], vv[q] * vv[q]);
    for (int off = 32; off > 0; off >>= 1) {
        ssq += __shfl_xor(ssq, off, 64);
        float ov = __shfl_xor(best, off, 64);
        int oi = __shfl_xor(bidx, off, 64);
        if (ov > best || (ov == best && oi < bidx)) { best = ov; bidx = oi; }
    }
    if (ln == 0) {
        ws[RNI_OFF + b * N1_ + r] = 1.f / fmaxf(sqrtf(ssq), 1e-12f);
        ((int*)ws)[BI_OFF + b * N1_ + r] = bidx;
    }
    __syncthreads();
    for (int c = t; c < N2_; c += 256)
        atomicAdd(&ws[CNI_OFF + b * N2_ + c], colacc[c]);
}

// ---------------- fin: col ssq -> reciprocal norm (in place) ----------------
// grid (B), block 384
__global__ void k_fin(float* __restrict__ ws) {
    int b = blockIdx.x, t = threadIdx.x;
    float v = ws[CNI_OFF + b * N2_ + t];
    ws[CNI_OFF + b * N2_ + t] = 1.f / fmaxf(sqrtf(v), 1e-12f);
}

// ---------------- fused mask scan ----------------
// flat grid 8192, block 256.
// XCD-aware decode: all 64 tiles of a batch land on the same XCD (d%8 const per batch)
// mask streams are nontemporal (single-use); att/cninv stay cache-resident.
#define EWS 132
__global__ __launch_bounds__(256, 4)
void k_scan(const float* __restrict__ att, const float* __restrict__ mapping,
            const float* __restrict__ samelb, float* __restrict__ ws) {
    __shared__ float ew[8 * EWS];
    __shared__ float rt[4], rb[4];
    int d = blockIdx.x;
    int xcd = d & 7, kk = d >> 3;
    int b = xcd * 16 + (kk >> 6);                 // 16 batches per XCD
    int tile = kk & 63;                           // 0..63 within batch
    int t = threadIdx.x;
    float top = 0.f, bot = 0.f;
    int r = t >> 5, c4 = t & 31;                  // r: 0..7 row-in-tile, c4: float4 col
    if (tile < 16) {
        // type A: mask rows [0,128) in 8-row tiles. cols<128: count; cols>=128: exp(-att*cninv)
        int i0 = tile * 8;
        const float4* m4 = (const float4*)(mapping + ((size_t)b * N_ + i0) * N_);
        const float4* s4 = (const float4*)(samelb + ((size_t)b * N_ + i0) * N_);
        const float4* a4 = (const float4*)(att + ((size_t)b * N1_ + i0) * N2_);
        const float4* cn4 = (const float4*)(ws + CNI_OFF + (size_t)b * N2_);
        float4 md = ntl4(&m4[r * 128 + c4]);
        float4 sd = ntl4(&s4[r * 128 + c4]);
        float4 av[3], mv[3], sv[3], cn[3];
        #pragma unroll
        for (int k = 0; k < 3; ++k) {
            int c = c4 + 32 * k;
            av[k] = a4[r * 96 + c];
            mv[k] = ntl4(&m4[r * 128 + 32 + c]);
            sv[k] = ntl4(&s4[r * 128 + 32 + c]);
            cn[k] = cn4[c];
        }
        top = md.x + md.y + md.z + md.w;
        bot = sd.x + sd.y + sd.z + sd.w;
        #pragma unroll
        for (int k = 0; k < 3; ++k) {
            float e0 = __expf(-av[k].x * cn[k].x);
            float e1 = __expf(-av[k].y * cn[k].y);
            float e2 = __expf(-av[k].z * cn[k].z);
            float e3 = __expf(-av[k].w * cn[k].w);
            top += mv[k].x * e0 + mv[k].y * e1 + mv[k].z * e2 + mv[k].w * e3;
            bot += sv[k].x * e0 + sv[k].y * e1 + sv[k].z * e2 + sv[k].w * e3;
        }
    } else {
        // type B: mask rows [128,512) in 8-row tiles; ew[rr][j] = exp(-att[j][cr0+rr]*rinv[j])
        int tb = tile - 16;                       // 0..47
        int cr0 = tb * 8;
        const float4* a4 = (const float4*)(att + (size_t)b * N1_ * N2_);
        {
            int j = t >> 1, q = t & 1;
            float4 a = a4[j * 96 + tb * 2 + q];
            float rv = ws[RNI_OFF + b * N1_ + j];
            ew[(4 * q + 0) * EWS + j] = __expf(-a.x * rv);
            ew[(4 * q + 1) * EWS + j] = __expf(-a.y * rv);
            ew[(4 * q + 2) * EWS + j] = __expf(-a.z * rv);
            ew[(4 * q + 3) * EWS + j] = __expf(-a.w * rv);
        }
        const float4* m4 = (const float4*)(mapping + ((size_t)b * N_ + N1_ + cr0) * N_);
        const float4* s4 = (const float4*)(samelb + ((size_t)b * N_ + N1_ + cr0) * N_);
        // independent mask loads issued before the ew barrier
        float4 mL = ntl4(&m4[r * 128 + c4]);
        float4 sL = ntl4(&s4[r * 128 + c4]);
        float4 mR[3], sR[3];
        #pragma unroll
        for (int k = 0; k < 3; ++k) {
            int c = c4 + 32 * k;
            mR[k] = ntl4(&m4[r * 128 + 32 + c]);
            sR[k] = ntl4(&s4[r * 128 + 32 + c]);
        }
        __syncthreads();
        float4 w = *(const float4*)&ew[r * EWS + c4 * 4];
        top = mL.x * w.x + mL.y * w.y + mL.z * w.z + mL.w * w.w;
        bot = sL.x * w.x + sL.y * w.y + sL.z * w.z + sL.w * w.w;
        #pragma unroll
        for (int k = 0; k < 3; ++k) {
            top += mR[k].x + mR[k].y + mR[k].z + mR[k].w;
            bot += sR[k].x + sR[k].y + sR[k].z + sR[k].w;
        }
    }
    for (int off = 32; off > 0; off >>= 1) {
        top += __shfl_down(top, off, 64);
        bot += __shfl_down(bot, off, 64);
    }
    int wv = t >> 6, ln = t & 63;
    if (ln == 0) { rt[wv] = top; rb[wv] = bot; }
    __syncthreads();
    if (t == 0) {
        atomicAdd(&ws[ACC_TOP + b], rt[0] + rt[1] + rt[2] + rt[3]);
        atomicAdd(&ws[ACC_BOT + b], rb[0] + rb[1] + rb[2] + rb[3]);
    }
}

// ---------------- back: kabsch+pair+finalize (y==0) | scores MLP (y==1) ----------------
__device__ inline float bred(float* s2, float v, int t) {
    for (int off = 32; off > 0; off >>= 1) v += __shfl_down(v, off, 64);
    if ((t & 63) == 0) s2[t >> 6] = v;
    __syncthreads();
    float r = s2[0] + s2[1];
    __syncthreads();
    return r;
}

// grid (B, 2), block 128
__global__ void k_back(const float* __restrict__ coords, const float* __restrict__ upd,
                       const float* __restrict__ nm, const int* __restrict__ ei,
                       const float* __restrict__ W0, const float* __restrict__ b0,
                       const float* __restrict__ W1, const float* __restrict__ b1,
                       const float* __restrict__ W2, const float* __restrict__ b2,
                       const float* __restrict__ W3, const float* __restrict__ b3,
                       const float* __restrict__ ws, float* __restrict__ out) {
    __shared__ float sh[2 * DFC];
    int b = blockIdx.x, t = threadIdx.x;
    if (blockIdx.y == 1) {
        // ---- scores MLP ----
        float* pool = sh;           // 64
        float* h    = sh + 64;      // 128
        __shared__ float part[DFC];
        if (t < DIN) pool[t] = ws[POOL_OFF + b * DIN + t] * (1.0f / 128.0f);
        __syncthreads();
        float a = b0[t];
        #pragma unroll
        for (int i = 0; i < DIN; ++i) a += pool[i] * W0[i * DFC + t];
        float hv = fmaxf(a, 0.f);
        __syncthreads(); h[t] = hv; __syncthreads();
        a = b1[t];
        #pragma unroll
        for (int i = 0; i < DFC; ++i) a += h[i] * W1[i * DFC + t];
        hv = fmaxf(a, 0.f);
        __syncthreads(); h[t] = hv; __syncthreads();
        a = b2[t];
        #pragma unroll
        for (int i = 0; i < DFC; ++i) a += h[i] * W2[i * DFC + t];
        part[t] = fmaxf(a, 0.f) * W3[t];
        __syncthreads();
        for (int off = 64; off > 0; off >>= 1) { if (t < off) part[t] += part[t + off]; __syncthreads(); }
        if (t == 0) out[b] = 1.f / (1.f + expf(-(part[0] + b3[0])));
        return;
    }
    // ---- Kabsch ----
    float* s2 = sh;
    __shared__ float Rsh[9], Tsh[3];
    int bidx = ((const int*)ws)[BI_OFF + b * N1_ + t];
    float P[3], Q[3];
    const float* up = upd + ((size_t)b * N_ + t) * 3;
    P[0] = up[0]; P[1] = up[1]; P[2] = up[2];
    const float* qp = coords + ((size_t)b * N_ + N1_ + bidx) * 3;
    Q[0] = qp[0]; Q[1] = qp[1]; Q[2] = qp[2];
    float Pm[3], Qm[3];
    for (int a = 0; a < 3; ++a) Pm[a] = bred(s2, P[a], t) * (1.f / 128.f);
    for (int a = 0; a < 3; ++a) Qm[a] = bred(s2, Q[a], t) * (1.f / 128.f);
    float H[9];
    for (int a = 0; a < 3; ++a)
        for (int c = 0; c < 3; ++c)
            H[a * 3 + c] = bred(s2, (P[a] - Pm[a]) * (Q[c] - Qm[c]), t) * (1.f / 8.f);
    if (t == 0) {
        double Hd[3][3];
        for (int a = 0; a < 3; ++a) for (int c = 0; c < 3; ++c) Hd[a][c] = (double)H[a * 3 + c];
        double A[3][3], V[3][3] = {{1,0,0},{0,1,0},{0,0,1}};
        for (int i = 0; i < 3; ++i)
            for (int j = 0; j < 3; ++j) {
                double z = 0; for (int c = 0; c < 3; ++c) z += Hd[c][i] * Hd[c][j];
                A[i][j] = z;
            }
        for (int sweep = 0; sweep < 8; ++sweep) {
            const int PQ[3][2] = {{0,1},{0,2},{1,2}};
            for (int r = 0; r < 3; ++r) {
                int p = PQ[r][0], q = PQ[r][1];
                double apq = A[p][q];
                if (fabs(apq) < 1e-300) continue;
                double tau = (A[q][q] - A[p][p]) / (2.0 * apq);
                double tt = (tau >= 0 ? 1.0 : -1.0) / (fabs(tau) + sqrt(1.0 + tau * tau));
                double c = 1.0 / sqrt(1.0 + tt * tt), s = tt * c;
                for (int k = 0; k < 3; ++k) { double akp = A[k][p], akq = A[k][q]; A[k][p] = c * akp - s * akq; A[k][q] = s * akp + c * akq; }
                for (int k = 0; k < 3; ++k) { double apk = A[p][k], aqk = A[q][k]; A[p][k] = c * apk - s * aqk; A[q][k] = s * apk + c * aqk; }
                for (int k = 0; k < 3; ++k) { double vkp = V[k][p], vkq = V[k][q]; V[k][p] = c * vkp - s * vkq; V[k][q] = s * vkp + c * vkq; }
            }
        }
        double lam[3] = {A[0][0], A[1][1], A[2][2]};
        int id[3] = {0, 1, 2};
        if (lam[id[0]] < lam[id[1]]) { int x = id[0]; id[0] = id[1]; id[1] = x; }
        if (lam[id[0]] < lam[id[2]]) { int x = id[0]; id[0] = id[2]; id[2] = x; }
        if (lam[id[1]] < lam[id[2]]) { int x = id[1]; id[1] = id[2]; id[2] = x; }
        double u[3][3], v[3][3], sv[3];
        for (int i = 0; i < 3; ++i) {
            for (int k = 0; k < 3; ++k) v[i][k] = V[k][id[i]];
            double uv[3];
            for (int c = 0; c < 3; ++c) uv[c] = Hd[c][0] * v[i][0] + Hd[c][1] * v[i][1] + Hd[c][2] * v[i][2];
            double n = sqrt(uv[0] * uv[0] + uv[1] * uv[1] + uv[2] * uv[2]);
            sv[i] = n;
            if (n > 1e-150) { u[i][0] = uv[0] / n; u[i][1] = uv[1] / n; u[i][2] = uv[2] / n; }
            else { u[i][0] = u[i][1] = u[i][2] = 0.0; }
        }
        if (sv[2] < 1e-12 * fmax(sv[0], 1e-300)) {
            u[2][0] = u[0][1] * u[1][2] - u[0][2] * u[1][1];
            u[2][1] = u[0][2] * u[1][0] - u[0][0] * u[1][2];
            u[2][2] = u[0][0] * u[1][1] - u[0][1] * u[1][0];
        }
        double det = Hd[0][0] * (Hd[1][1] * Hd[2][2] - Hd[1][2] * Hd[2][1])
                   - Hd[0][1] * (Hd[1][0] * Hd[2][2] - Hd[1][2] * Hd[2][0])
                   + Hd[0][2] * (Hd[1][0] * Hd[2][1] - Hd[1][1] * Hd[2][0]);
        double dsg = (det > 0.0) ? 1.0 : ((det < 0.0) ? -1.0 : 0.0);
        for (int a = 0; a < 3; ++a)
            for (int c = 0; c < 3; ++c)
                Rsh[a * 3 + c] = (float)(u[0][a] * v[0][c] + u[1][a] * v[1][c] + dsg * u[2][a] * v[2][c]);
        for (int a = 0; a < 3; ++a)
            Tsh[a] = Qm[a] - (Rsh[a * 3] * Pm[0] + Rsh[a * 3 + 1] * Pm[1] + Rsh[a * 3 + 2] * Pm[2]);
    }
    __syncthreads();
    float Pp[3];
    for (int a = 0; a < 3; ++a)
        Pp[a] = Rsh[a * 3] * P[0] + Rsh[a * 3 + 1] * P[1] + Rsh[a * 3 + 2] * P[2] + Tsh[a];
    float mk = (nm[b * N1_ + t] > 0.5f) ? 1.f : 0.f;
    float dx = Pp[0] - Q[0], dy = Pp[1] - Q[1], dz = Pp[2] - Q[2];
    float rsum = bred(s2, mk * (dx * dx + dy * dy + dz * dz), t);
    float msum = bred(s2, mk, t);
    float Ppm[3];
    for (int a = 0; a < 3; ++a) Ppm[a] = bred(s2, Pp[a], t) * (1.f / 128.f);
    if (t == 0) {
        float cnt = fmaxf(msum * 3.f, 1.f);
        atomicAdd(&out[129], (rsum / cnt) * (1.f / 128.f));
        float cen = 0.f;
        for (int a = 0; a < 3; ++a) { float d2 = Ppm[a] - Qm[a]; cen += d2 * d2; }
        atomicAdd(&out[131], (cen / 3.f) * (1.f / 128.f));
    }
    // ---- fused pairdst ----
    const float* C = coords + (size_t)b * N_ * 3;
    const float* U = upd + (size_t)b * N_ * 3;
    const int* e = ei + (size_t)b * E_ * 2;
    float acc = 0.f;
    for (int idx = t; idx < E_; idx += 128) {
        int a0 = e[idx * 2], a1 = e[idx * 2 + 1];
        float ex = C[a0 * 3] - C[a1 * 3], ey = C[a0 * 3 + 1] - C[a1 * 3 + 1], ez = C[a0 * 3 + 2] - C[a1 * 3 + 2];
        float d0 = sqrtf(ex * ex + ey * ey + ez * ez + 1e-12f);
        ex = U[a0 * 3] - U[a1 * 3]; ey = U[a0 * 3 + 1] - U[a1 * 3 + 1]; ez = U[a0 * 3 + 2] - U[a1 * 3 + 2];
        float d1 = sqrtf(ex * ex + ey * ey + ez * ez + 1e-12f);
        acc += d1 - d0;
    }
    float psum = bred(s2, acc, t);
    if (t == 0) atomicAdd(&out[130], fabsf(psum) * (1.f / 128.f));
    // ---- attn_loss finalize ----
    if (b == 0) {
        float top = ws[ACC_TOP + t], bot = ws[ACC_BOT + t];
        float v = top / (bot - top + 1.0f);
        float s = bred(s2, v, t);
        if (t == 0) out[128] = s * (1.0f / 128.0f);
    }
}

extern "C" void kernel_launch(void* const* d_in, const int* in_sizes, int n_in,
                              void* d_out, int out_size, void* d_ws, size_t ws_size,
                              hipStream_t stream) {
    const float* c_hs      = (const float*)d_in[0];
    const float* attention = (const float*)d_in[1];
    const float* coords    = (const float*)d_in[2];
    const float* upd       = (const float*)d_in[3];
    const float* c_valid   = (const float*)d_in[4];
    const float* nm        = (const float*)d_in[5];
    const float* mapping   = (const float*)d_in[6];
    const float* samelb    = (const float*)d_in[7];
    const int*   ei        = (const int*)d_in[8];
    const float* W0 = (const float*)d_in[9],  *b0 = (const float*)d_in[10];
    const float* W1 = (const float*)d_in[11], *b1 = (const float*)d_in[12];
    const float* W2 = (const float*)d_in[13], *b2 = (const float*)d_in[14];
    const float* W3 = (const float*)d_in[15], *b3 = (const float*)d_in[16];
    float* out = (float*)d_out;
    float* ws  = (float*)d_ws;

    hipLaunchKernelGGL(k_init,  dim3(192),     dim3(256), 0, stream, ws, out);
    hipLaunchKernelGGL(k_front, dim3(B_, 40),  dim3(256), 0, stream, c_hs, c_valid, attention, ws);
    hipLaunchKernelGGL(k_fin,   dim3(B_),      dim3(N2_), 0, stream, ws);
    hipLaunchKernelGGL(k_scan,  dim3(8192),    dim3(256), 0, stream, attention, mapping, samelb, ws);
    hipLaunchKernelGGL(k_back,  dim3(B_, 2),   dim3(128), 0, stream, coords, upd, nm, ei,
                       W0, b0, W1, b1, W2, b2, W3, b3, ws, out);
}

// Round 4
// 359.279 us; speedup vs baseline: 1.0846x; 1.0137x over previous
//
#include <hip/hip_runtime.h>
#include <math.h>

#define B_   128
#define N1_  128
#define N2_  384
#define N_   512
#define E_   1024
#define DIN  64
#define DFC  128

// workspace layout (floats)
#define ACC_TOP  0
#define ACC_BOT  128
#define POOL_OFF 256                          // B*64 = 8192
#define RNI_OFF  (POOL_OFF + B_*DIN)          // 8448:  B*N1 reciprocal rownorms
#define BI_OFF   (RNI_OFF + B_*N1_)           // 24832: B*N1 argmax ints
#define CNI_OFF  (BI_OFF + B_*N1_)            // 41216: B*N2 reciprocal colnorms

// nontemporal float4 load (native ext_vector type required by the builtin)
typedef float f4v __attribute__((ext_vector_type(4)));
__device__ __forceinline__ float4 ntl4(const float4* p) {
    f4v v = __builtin_nontemporal_load((const f4v*)p);
    float4 r; r.x = v.x; r.y = v.y; r.z = v.z; r.w = v.w;
    return r;
}

// ---------------- pre: pool (y==0) | att stats rownorm+argmax+colnorm (y==1) ----------------
// grid (B, 2), block 256.  One block per batch per role -> no global atomics, no init pass.
// Linear block id = b + 128*y, 128%8==0 -> batch b always on XCD b&7 (matches k_scan decode).
__global__ void k_pre(const float* __restrict__ c_hs, const float* __restrict__ c_valid,
                      const float* __restrict__ att, float* __restrict__ ws,
                      float* __restrict__ out) {
    __shared__ float4 sred4[256];        // pool reduce
    __shared__ float colp[8][N2_];       // att col-ssq partials (12 KB)
    int b = blockIdx.x, t = threadIdx.x;
    if (blockIdx.y == 0) {
        // zero the cross-kernel accumulators (k_scan / k_back add into these later)
        if (t == 0) { ws[ACC_TOP + b] = 0.f; ws[ACC_BOT + b] = 0.f; }
        if (b == 0 && t < 4) out[128 + t] = 0.f;
        // masked mean-pool over all 512 rows (c_hs single-use -> nontemporal)
        int d4 = t & 15, rl = t >> 4;
        const float4* X4 = (const float4*)(c_hs + (size_t)b * N_ * DIN);
        const float* V = c_valid + (size_t)b * N_;
        float4 acc = {0.f, 0.f, 0.f, 0.f};
        for (int r = rl; r < N_; r += 16) {
            float4 x = ntl4(&X4[r * 16 + d4]);
            float v = V[r];
            acc.x += x.x * v; acc.y += x.y * v; acc.z += x.z * v; acc.w += x.w * v;
        }
        sred4[t] = acc; __syncthreads();
        for (int off = 128; off >= 16; off >>= 1) {
            if (t < off) {
                float4 o = sred4[t + off];
                sred4[t].x += o.x; sred4[t].y += o.y; sred4[t].z += o.z; sred4[t].w += o.w;
            }
            __syncthreads();
        }
        if (t < 16) {
            float4 s = sred4[t];
            float* p = ws + POOL_OFF + b * DIN + t * 4;
            p[0] = s.x; p[1] = s.y; p[2] = s.z; p[3] = s.w;
        }
        return;
    }
    // ---- y==1: att stats. 8 row-groups x 32 lanes; regular loads keep att warm in this XCD's L2
    int lane = t & 31, grp = t >> 5;
    const float4* a4 = (const float4*)(att + (size_t)b * N1_ * N2_);
    float4 cs[3] = {{0,0,0,0},{0,0,0,0},{0,0,0,0}};
    for (int rr = 0; rr < N1_; rr += 8) {
        int r = rr + grp;
        float ssq = 0.f, best = -1e30f; int bidx = 0;
        #pragma unroll
        for (int c = 0; c < 3; ++c) {
            float4 v = a4[(size_t)r * 96 + c * 32 + lane];
            cs[c].x += v.x * v.x; cs[c].y += v.y * v.y;
            cs[c].z += v.z * v.z; cs[c].w += v.w * v.w;
            ssq += v.x * v.x + v.y * v.y + v.z * v.z + v.w * v.w;
            int cb = (c * 32 + lane) * 4;          // ascending within thread
            if (v.x > best) { best = v.x; bidx = cb; }
            if (v.y > best) { best = v.y; bidx = cb + 1; }
            if (v.z > best) { best = v.z; bidx = cb + 2; }
            if (v.w > best) { best = v.w; bidx = cb + 3; }
        }
        // reduce across the 32-lane row group (xor<=16 stays in group)
        for (int off = 16; off > 0; off >>= 1) {
            ssq += __shfl_xor(ssq, off, 64);
            float ov = __shfl_xor(best, off, 64);
            int oi = __shfl_xor(bidx, off, 64);
            if (ov > best || (ov == best && oi < bidx)) { best = ov; bidx = oi; }
        }
        if (lane == 0) {
            ws[RNI_OFF + b * N1_ + r] = 1.f / fmaxf(sqrtf(ssq), 1e-12f);
            ((int*)ws)[BI_OFF + b * N1_ + r] = bidx;
        }
    }
    #pragma unroll
    for (int c = 0; c < 3; ++c) {
        int fc = (c * 32 + lane) * 4;
        colp[grp][fc]     = cs[c].x;
        colp[grp][fc + 1] = cs[c].y;
        colp[grp][fc + 2] = cs[c].z;
        colp[grp][fc + 3] = cs[c].w;
    }
    __syncthreads();
    for (int cc = t; cc < N2_; cc += 256) {
        float s = colp[0][cc] + colp[1][cc] + colp[2][cc] + colp[3][cc]
                + colp[4][cc] + colp[5][cc] + colp[6][cc] + colp[7][cc];
        ws[CNI_OFF + b * N2_ + cc] = 1.f / fmaxf(sqrtf(s), 1e-12f);
    }
}

// ---------------- fused mask scan ----------------
// flat grid 8192, block 256.
// XCD decode: batch b = xcd + 8*q  ->  b&7 == xcd, matching k_pre's placement (warm att in L2).
// mask streams nontemporal (single-use); att/cninv/rinv L2-resident.
#define EWS 132
__global__ __launch_bounds__(256, 4)
void k_scan(const float* __restrict__ att, const float* __restrict__ mapping,
            const float* __restrict__ samelb, float* __restrict__ ws) {
    __shared__ float ew[8 * EWS];
    __shared__ float rt[4], rb[4];
    int d = blockIdx.x;
    int xcd = d & 7, kk = d >> 3;
    int b = xcd + 8 * (kk >> 6);                  // batch -> XCD b&7
    int tile = kk & 63;                           // 0..63 within batch
    int t = threadIdx.x;
    float top = 0.f, bot = 0.f;
    int r = t >> 5, c4 = t & 31;                  // r: 0..7 row-in-tile, c4: float4 col
    if (tile < 16) {
        // type A: mask rows [0,128): cols<128 count; cols>=128 exp(-att*cninv)
        int i0 = tile * 8;
        const float4* m4 = (const float4*)(mapping + ((size_t)b * N_ + i0) * N_);
        const float4* s4 = (const float4*)(samelb + ((size_t)b * N_ + i0) * N_);
        const float4* a4 = (const float4*)(att + ((size_t)b * N1_ + i0) * N2_);
        const float4* cn4 = (const float4*)(ws + CNI_OFF + (size_t)b * N2_);
        float4 md = ntl4(&m4[r * 128 + c4]);
        float4 sd = ntl4(&s4[r * 128 + c4]);
        float4 av[3], mv[3], sv[3], cn[3];
        #pragma unroll
        for (int k = 0; k < 3; ++k) {
            int c = c4 + 32 * k;
            av[k] = a4[r * 96 + c];
            mv[k] = ntl4(&m4[r * 128 + 32 + c]);
            sv[k] = ntl4(&s4[r * 128 + 32 + c]);
            cn[k] = cn4[c];
        }
        top = md.x + md.y + md.z + md.w;
        bot = sd.x + sd.y + sd.z + sd.w;
        #pragma unroll
        for (int k = 0; k < 3; ++k) {
            float e0 = __expf(-av[k].x * cn[k].x);
            float e1 = __expf(-av[k].y * cn[k].y);
            float e2 = __expf(-av[k].z * cn[k].z);
            float e3 = __expf(-av[k].w * cn[k].w);
            top += mv[k].x * e0 + mv[k].y * e1 + mv[k].z * e2 + mv[k].w * e3;
            bot += sv[k].x * e0 + sv[k].y * e1 + sv[k].z * e2 + sv[k].w * e3;
        }
    } else {
        // type B: mask rows [128,512); ew[rr][j] = exp(-att[j][cr0+rr]*rinv[j])
        int tb = tile - 16;                       // 0..47
        int cr0 = tb * 8;
        const float4* a4 = (const float4*)(att + (size_t)b * N1_ * N2_);
        {
            int j = t >> 1, q = t & 1;
            float4 a = a4[j * 96 + tb * 2 + q];
            float rv = ws[RNI_OFF + b * N1_ + j];
            ew[(4 * q + 0) * EWS + j] = __expf(-a.x * rv);
            ew[(4 * q + 1) * EWS + j] = __expf(-a.y * rv);
            ew[(4 * q + 2) * EWS + j] = __expf(-a.z * rv);
            ew[(4 * q + 3) * EWS + j] = __expf(-a.w * rv);
        }
        const float4* m4 = (const float4*)(mapping + ((size_t)b * N_ + N1_ + cr0) * N_);
        const float4* s4 = (const float4*)(samelb + ((size_t)b * N_ + N1_ + cr0) * N_);
        float4 mL = ntl4(&m4[r * 128 + c4]);
        float4 sL = ntl4(&s4[r * 128 + c4]);
        float4 mR[3], sR[3];
        #pragma unroll
        for (int k = 0; k < 3; ++k) {
            int c = c4 + 32 * k;
            mR[k] = ntl4(&m4[r * 128 + 32 + c]);
            sR[k] = ntl4(&s4[r * 128 + 32 + c]);
        }
        __syncthreads();
        float4 w = *(const float4*)&ew[r * EWS + c4 * 4];
        top = mL.x * w.x + mL.y * w.y + mL.z * w.z + mL.w * w.w;
        bot = sL.x * w.x + sL.y * w.y + sL.z * w.z + sL.w * w.w;
        #pragma unroll
        for (int k = 0; k < 3; ++k) {
            top += mR[k].x + mR[k].y + mR[k].z + mR[k].w;
            bot += sR[k].x + sR[k].y + sR[k].z + sR[k].w;
        }
    }
    for (int off = 32; off > 0; off >>= 1) {
        top += __shfl_down(top, off, 64);
        bot += __shfl_down(bot, off, 64);
    }
    int wv = t >> 6, ln = t & 63;
    if (ln == 0) { rt[wv] = top; rb[wv] = bot; }
    __syncthreads();
    if (t == 0) {
        atomicAdd(&ws[ACC_TOP + b], rt[0] + rt[1] + rt[2] + rt[3]);
        atomicAdd(&ws[ACC_BOT + b], rb[0] + rb[1] + rb[2] + rb[3]);
    }
}

// ---------------- back: kabsch+pair+finalize (y==0) | scores MLP (y==1) ----------------
__device__ inline float bred(float* s2, float v, int t) {
    for (int off = 32; off > 0; off >>= 1) v += __shfl_down(v, off, 64);
    if ((t & 63) == 0) s2[t >> 6] = v;
    __syncthreads();
    float r = s2[0] + s2[1];
    __syncthreads();
    return r;
}

// grid (B, 2), block 128
__global__ void k_back(const float* __restrict__ coords, const float* __restrict__ upd,
                       const float* __restrict__ nm, const int* __restrict__ ei,
                       const float* __restrict__ W0, const float* __restrict__ b0,
                       const float* __restrict__ W1, const float* __restrict__ b1,
                       const float* __restrict__ W2, const float* __restrict__ b2,
                       const float* __restrict__ W3, const float* __restrict__ b3,
                       const float* __restrict__ ws, float* __restrict__ out) {
    __shared__ float sh[2 * DFC];
    int b = blockIdx.x, t = threadIdx.x;
    if (blockIdx.y == 1) {
        // ---- scores MLP ----
        float* pool = sh;           // 64
        float* h    = sh + 64;      // 128
        __shared__ float part[DFC];
        if (t < DIN) pool[t] = ws[POOL_OFF + b * DIN + t] * (1.0f / 128.0f);
        __syncthreads();
        float a = b0[t];
        #pragma unroll
        for (int i = 0; i < DIN; ++i) a += pool[i] * W0[i * DFC + t];
        float hv = fmaxf(a, 0.f);
        __syncthreads(); h[t] = hv; __syncthreads();
        a = b1[t];
        #pragma unroll
        for (int i = 0; i < DFC; ++i) a += h[i] * W1[i * DFC + t];
        hv = fmaxf(a, 0.f);
        __syncthreads(); h[t] = hv; __syncthreads();
        a = b2[t];
        #pragma unroll
        for (int i = 0; i < DFC; ++i) a += h[i] * W2[i * DFC + t];
        part[t] = fmaxf(a, 0.f) * W3[t];
        __syncthreads();
        for (int off = 64; off > 0; off >>= 1) { if (t < off) part[t] += part[t + off]; __syncthreads(); }
        if (t == 0) out[b] = 1.f / (1.f + expf(-(part[0] + b3[0])));
        return;
    }
    // ---- Kabsch ----
    float* s2 = sh;
    __shared__ float Rsh[9], Tsh[3];
    int bidx = ((const int*)ws)[BI_OFF + b * N1_ + t];
    float P[3], Q[3];
    const float* up = upd + ((size_t)b * N_ + t) * 3;
    P[0] = up[0]; P[1] = up[1]; P[2] = up[2];
    const float* qp = coords + ((size_t)b * N_ + N1_ + bidx) * 3;
    Q[0] = qp[0]; Q[1] = qp[1]; Q[2] = qp[2];
    float Pm[3], Qm[3];
    for (int a = 0; a < 3; ++a) Pm[a] = bred(s2, P[a], t) * (1.f / 128.f);
    for (int a = 0; a < 3; ++a) Qm[a] = bred(s2, Q[a], t) * (1.f / 128.f);
    float H[9];
    for (int a = 0; a < 3; ++a)
        for (int c = 0; c < 3; ++c)
            H[a * 3 + c] = bred(s2, (P[a] - Pm[a]) * (Q[c] - Qm[c]), t) * (1.f / 8.f);
    if (t == 0) {
        double Hd[3][3];
        for (int a = 0; a < 3; ++a) for (int c = 0; c < 3; ++c) Hd[a][c] = (double)H[a * 3 + c];
        double A[3][3], V[3][3] = {{1,0,0},{0,1,0},{0,0,1}};
        for (int i = 0; i < 3; ++i)
            for (int j = 0; j < 3; ++j) {
                double z = 0; for (int c = 0; c < 3; ++c) z += Hd[c][i] * Hd[c][j];
                A[i][j] = z;
            }
        for (int sweep = 0; sweep < 8; ++sweep) {
            const int PQ[3][2] = {{0,1},{0,2},{1,2}};
            for (int r = 0; r < 3; ++r) {
                int p = PQ[r][0], q = PQ[r][1];
                double apq = A[p][q];
                if (fabs(apq) < 1e-300) continue;
                double tau = (A[q][q] - A[p][p]) / (2.0 * apq);
                double tt = (tau >= 0 ? 1.0 : -1.0) / (fabs(tau) + sqrt(1.0 + tau * tau));
                double c = 1.0 / sqrt(1.0 + tt * tt), s = tt * c;
                for (int k = 0; k < 3; ++k) { double akp = A[k][p], akq = A[k][q]; A[k][p] = c * akp - s * akq; A[k][q] = s * akp + c * akq; }
                for (int k = 0; k < 3; ++k) { double apk = A[p][k], aqk = A[q][k]; A[p][k] = c * apk - s * aqk; A[q][k] = s * apk + c * aqk; }
                for (int k = 0; k < 3; ++k) { double vkp = V[k][p], vkq = V[k][q]; V[k][p] = c * vkp - s * vkq; V[k][q] = s * vkp + c * vkq; }
            }
        }
        double lam[3] = {A[0][0], A[1][1], A[2][2]};
        int id[3] = {0, 1, 2};
        if (lam[id[0]] < lam[id[1]]) { int x = id[0]; id[0] = id[1]; id[1] = x; }
        if (lam[id[0]] < lam[id[2]]) { int x = id[0]; id[0] = id[2]; id[2] = x; }
        if (lam[id[1]] < lam[id[2]]) { int x = id[1]; id[1] = id[2]; id[2] = x; }
        double u[3][3], v[3][3], sv[3];
        for (int i = 0; i < 3; ++i) {
            for (int k = 0; k < 3; ++k) v[i][k] = V[k][id[i]];
            double uv[3];
            for (int c = 0; c < 3; ++c) uv[c] = Hd[c][0] * v[i][0] + Hd[c][1] * v[i][1] + Hd[c][2] * v[i][2];
            double n = sqrt(uv[0] * uv[0] + uv[1] * uv[1] + uv[2] * uv[2]);
            sv[i] = n;
            if (n > 1e-150) { u[i][0] = uv[0] / n; u[i][1] = uv[1] / n; u[i][2] = uv[2] / n; }
            else { u[i][0] = u[i][1] = u[i][2] = 0.0; }
        }
        if (sv[2] < 1e-12 * fmax(sv[0], 1e-300)) {
            u[2][0] = u[0][1] * u[1][2] - u[0][2] * u[1][1];
            u[2][1] = u[0][2] * u[1][0] - u[0][0] * u[1][2];
            u[2][2] = u[0][0] * u[1][1] - u[0][1] * u[1][0];
        }
        double det = Hd[0][0] * (Hd[1][1] * Hd[2][2] - Hd[1][2] * Hd[2][1])
                   - Hd[0][1] * (Hd[1][0] * Hd[2][2] - Hd[1][2] * Hd[2][0])
                   + Hd[0][2] * (Hd[1][0] * Hd[2][1] - Hd[1][1] * Hd[2][0]);
        double dsg = (det > 0.0) ? 1.0 : ((det < 0.0) ? -1.0 : 0.0);
        for (int a = 0; a < 3; ++a)
            for (int c = 0; c < 3; ++c)
                Rsh[a * 3 + c] = (float)(u[0][a] * v[0][c] + u[1][a] * v[1][c] + dsg * u[2][a] * v[2][c]);
        for (int a = 0; a < 3; ++a)
            Tsh[a] = Qm[a] - (Rsh[a * 3] * Pm[0] + Rsh[a * 3 + 1] * Pm[1] + Rsh[a * 3 + 2] * Pm[2]);
    }
    __syncthreads();
    float Pp[3];
    for (int a = 0; a < 3; ++a)
        Pp[a] = Rsh[a * 3] * P[0] + Rsh[a * 3 + 1] * P[1] + Rsh[a * 3 + 2] * P[2] + Tsh[a];
    float mk = (nm[b * N1_ + t] > 0.5f) ? 1.f : 0.f;
    float dx = Pp[0] - Q[0], dy = Pp[1] - Q[1], dz = Pp[2] - Q[2];
    float rsum = bred(s2, mk * (dx * dx + dy * dy + dz * dz), t);
    float msum = bred(s2, mk, t);
    float Ppm[3];
    for (int a = 0; a < 3; ++a) Ppm[a] = bred(s2, Pp[a], t) * (1.f / 128.f);
    if (t == 0) {
        float cnt = fmaxf(msum * 3.f, 1.f);
        atomicAdd(&out[129], (rsum / cnt) * (1.f / 128.f));
        float cen = 0.f;
        for (int a = 0; a < 3; ++a) { float d2 = Ppm[a] - Qm[a]; cen += d2 * d2; }
        atomicAdd(&out[131], (cen / 3.f) * (1.f / 128.f));
    }
    // ---- fused pairdst ----
    const float* C = coords + (size_t)b * N_ * 3;
    const float* U = upd + (size_t)b * N_ * 3;
    const int* e = ei + (size_t)b * E_ * 2;
    float acc = 0.f;
    for (int idx = t; idx < E_; idx += 128) {
        int a0 = e[idx * 2], a1 = e[idx * 2 + 1];
        float ex = C[a0 * 3] - C[a1 * 3], ey = C[a0 * 3 + 1] - C[a1 * 3 + 1], ez = C[a0 * 3 + 2] - C[a1 * 3 + 2];
        float d0 = sqrtf(ex * ex + ey * ey + ez * ez + 1e-12f);
        ex = U[a0 * 3] - U[a1 * 3]; ey = U[a0 * 3 + 1] - U[a1 * 3 + 1]; ez = U[a0 * 3 + 2] - U[a1 * 3 + 2];
        float d1 = sqrtf(ex * ex + ey * ey + ez * ez + 1e-12f);
        acc += d1 - d0;
    }
    float psum = bred(s2, acc, t);
    if (t == 0) atomicAdd(&out[130], fabsf(psum) * (1.f / 128.f));
    // ---- attn_loss finalize ----
    if (b == 0) {
        float top = ws[ACC_TOP + t], bot = ws[ACC_BOT + t];
        float v = top / (bot - top + 1.0f);
        float s = bred(s2, v, t);
        if (t == 0) out[128] = s * (1.0f / 128.0f);
    }
}

extern "C" void kernel_launch(void* const* d_in, const int* in_sizes, int n_in,
                              void* d_out, int out_size, void* d_ws, size_t ws_size,
                              hipStream_t stream) {
    const float* c_hs      = (const float*)d_in[0];
    const float* attention = (const float*)d_in[1];
    const float* coords    = (const float*)d_in[2];
    const float* upd       = (const float*)d_in[3];
    const float* c_valid   = (const float*)d_in[4];
    const float* nm        = (const float*)d_in[5];
    const float* mapping   = (const float*)d_in[6];
    const float* samelb    = (const float*)d_in[7];
    const int*   ei        = (const int*)d_in[8];
    const float* W0 = (const float*)d_in[9],  *b0 = (const float*)d_in[10];
    const float* W1 = (const float*)d_in[11], *b1 = (const float*)d_in[12];
    const float* W2 = (const float*)d_in[13], *b2 = (const float*)d_in[14];
    const float* W3 = (const float*)d_in[15], *b3 = (const float*)d_in[16];
    float* out = (float*)d_out;
    float* ws  = (float*)d_ws;

    hipLaunchKernelGGL(k_pre,  dim3(B_, 2), dim3(256), 0, stream, c_hs, c_valid, attention, ws, out);
    hipLaunchKernelGGL(k_scan, dim3(8192),  dim3(256), 0, stream, attention, mapping, samelb, ws);
    hipLaunchKernelGGL(k_back, dim3(B_, 2), dim3(128), 0, stream, coords, upd, nm, ei,
                       W0, b0, W1, b1, W2, b2, W3, b3, ws, out);
}

// Round 5
// 350.154 us; speedup vs baseline: 1.1129x; 1.0261x over previous
//
#include <hip/hip_runtime.h>
#include <math.h>

#define B_   128
#define N1_  128
#define N2_  384
#define N_   512
#define E_   1024
#define DIN  64
#define DFC  128

// workspace layout (floats)
#define ACC_TOP  0
#define ACC_BOT  128
#define POOL_OFF 256                          // B*64 = 8192
#define RNI_OFF  (POOL_OFF + B_*DIN)          // 8448:  B*N1 reciprocal rownorms
#define BI_OFF   (RNI_OFF + B_*N1_)           // 24832: B*N1 argmax ints
#define CNI_OFF  (BI_OFF + B_*N1_)            // 41216: B*N2 reciprocal colnorms

// nontemporal float4 load (native ext_vector type required by the builtin)
typedef float f4v __attribute__((ext_vector_type(4)));
__device__ __forceinline__ float4 ntl4(const float4* p) {
    f4v v = __builtin_nontemporal_load((const f4v*)p);
    float4 r; r.x = v.x; r.y = v.y; r.z = v.z; r.w = v.w;
    return r;
}

// ---------------- pre: pool (y==0) | att stats rownorm+argmax+colnorm (y==1) ----------------
// grid (B, 2), block 512 (8 waves/CU for latency hiding; was 256 = 4 waves).
// One block per batch per role -> no global atomics, no init pass.
// Linear block id = b + 128*y, 128%8==0 -> batch b always on XCD b&7 (matches k_scan decode).
__global__ void k_pre(const float* __restrict__ c_hs, const float* __restrict__ c_valid,
                      const float* __restrict__ att, float* __restrict__ ws,
                      float* __restrict__ out) {
    __shared__ float4 sred4[512];        // pool reduce (8 KB)
    __shared__ float colp[16][N2_];      // att col-ssq partials (24 KB)
    int b = blockIdx.x, t = threadIdx.x;
    if (blockIdx.y == 0) {
        // zero the cross-kernel accumulators (k_scan / k_back add into these later)
        if (t == 0) { ws[ACC_TOP + b] = 0.f; ws[ACC_BOT + b] = 0.f; }
        if (b == 0 && t < 4) out[128 + t] = 0.f;
        // masked mean-pool over all 512 rows (c_hs single-use -> nontemporal)
        int d4 = t & 15, rl = t >> 4;            // rl: 0..31
        const float4* X4 = (const float4*)(c_hs + (size_t)b * N_ * DIN);
        const float* V = c_valid + (size_t)b * N_;
        float4 acc = {0.f, 0.f, 0.f, 0.f};
        for (int r = rl; r < N_; r += 32) {
            float4 x = ntl4(&X4[r * 16 + d4]);
            float v = V[r];
            acc.x += x.x * v; acc.y += x.y * v; acc.z += x.z * v; acc.w += x.w * v;
        }
        sred4[t] = acc; __syncthreads();
        for (int off = 256; off >= 16; off >>= 1) {
            if (t < off) {
                float4 o = sred4[t + off];
                sred4[t].x += o.x; sred4[t].y += o.y; sred4[t].z += o.z; sred4[t].w += o.w;
            }
            __syncthreads();
        }
        if (t < 16) {
            float4 s = sred4[t];
            float* p = ws + POOL_OFF + b * DIN + t * 4;
            p[0] = s.x; p[1] = s.y; p[2] = s.z; p[3] = s.w;
        }
        return;
    }
    // ---- y==1: att stats. 16 row-groups x 32 lanes; regular loads keep att warm in this XCD's L2
    int lane = t & 31, grp = t >> 5;             // grp: 0..15
    const float4* a4 = (const float4*)(att + (size_t)b * N1_ * N2_);
    float4 cs[3] = {{0,0,0,0},{0,0,0,0},{0,0,0,0}};
    for (int rr = 0; rr < N1_; rr += 16) {
        int r = rr + grp;
        float ssq = 0.f, best = -1e30f; int bidx = 0;
        #pragma unroll
        for (int c = 0; c < 3; ++c) {
            float4 v = a4[(size_t)r * 96 + c * 32 + lane];
            cs[c].x += v.x * v.x; cs[c].y += v.y * v.y;
            cs[c].z += v.z * v.z; cs[c].w += v.w * v.w;
            ssq += v.x * v.x + v.y * v.y + v.z * v.z + v.w * v.w;
            int cb = (c * 32 + lane) * 4;        // ascending within thread
            if (v.x > best) { best = v.x; bidx = cb; }
            if (v.y > best) { best = v.y; bidx = cb + 1; }
            if (v.z > best) { best = v.z; bidx = cb + 2; }
            if (v.w > best) { best = v.w; bidx = cb + 3; }
        }
        // reduce across the 32-lane row group (xor<=16 stays within the 32-lane half-wave)
        for (int off = 16; off > 0; off >>= 1) {
            ssq += __shfl_xor(ssq, off, 64);
            float ov = __shfl_xor(best, off, 64);
            int oi = __shfl_xor(bidx, off, 64);
            if (ov > best || (ov == best && oi < bidx)) { best = ov; bidx = oi; }
        }
        if (lane == 0) {
            ws[RNI_OFF + b * N1_ + r] = 1.f / fmaxf(sqrtf(ssq), 1e-12f);
            ((int*)ws)[BI_OFF + b * N1_ + r] = bidx;
        }
    }
    #pragma unroll
    for (int c = 0; c < 3; ++c) {
        int fc = (c * 32 + lane) * 4;
        colp[grp][fc]     = cs[c].x;
        colp[grp][fc + 1] = cs[c].y;
        colp[grp][fc + 2] = cs[c].z;
        colp[grp][fc + 3] = cs[c].w;
    }
    __syncthreads();
    for (int cc = t; cc < N2_; cc += 512) {
        float s = 0.f;
        #pragma unroll
        for (int g = 0; g < 16; ++g) s += colp[g][cc];
        ws[CNI_OFF + b * N2_ + cc] = 1.f / fmaxf(sqrtf(s), 1e-12f);
    }
}

// ---------------- fused mask scan ----------------
// flat grid 8192, block 256.
// XCD decode: batch b = xcd + 8*q  ->  b&7 == xcd, matching k_pre's placement (warm att in L2).
// mask streams nontemporal (single-use); att/cninv/rinv L2-resident.
#define EWS 132
__global__ __launch_bounds__(256, 4)
void k_scan(const float* __restrict__ att, const float* __restrict__ mapping,
            const float* __restrict__ samelb, float* __restrict__ ws) {
    __shared__ float ew[8 * EWS];
    __shared__ float rt[4], rb[4];
    int d = blockIdx.x;
    int xcd = d & 7, kk = d >> 3;
    int b = xcd + 8 * (kk >> 6);                  // batch -> XCD b&7
    int tile = kk & 63;                           // 0..63 within batch
    int t = threadIdx.x;
    float top = 0.f, bot = 0.f;
    int r = t >> 5, c4 = t & 31;                  // r: 0..7 row-in-tile, c4: float4 col
    if (tile < 16) {
        // type A: mask rows [0,128): cols<128 count; cols>=128 exp(-att*cninv)
        int i0 = tile * 8;
        const float4* m4 = (const float4*)(mapping + ((size_t)b * N_ + i0) * N_);
        const float4* s4 = (const float4*)(samelb + ((size_t)b * N_ + i0) * N_);
        const float4* a4 = (const float4*)(att + ((size_t)b * N1_ + i0) * N2_);
        const float4* cn4 = (const float4*)(ws + CNI_OFF + (size_t)b * N2_);
        float4 md = ntl4(&m4[r * 128 + c4]);
        float4 sd = ntl4(&s4[r * 128 + c4]);
        float4 av[3], mv[3], sv[3], cn[3];
        #pragma unroll
        for (int k = 0; k < 3; ++k) {
            int c = c4 + 32 * k;
            av[k] = a4[r * 96 + c];
            mv[k] = ntl4(&m4[r * 128 + 32 + c]);
            sv[k] = ntl4(&s4[r * 128 + 32 + c]);
            cn[k] = cn4[c];
        }
        top = md.x + md.y + md.z + md.w;
        bot = sd.x + sd.y + sd.z + sd.w;
        #pragma unroll
        for (int k = 0; k < 3; ++k) {
            float e0 = __expf(-av[k].x * cn[k].x);
            float e1 = __expf(-av[k].y * cn[k].y);
            float e2 = __expf(-av[k].z * cn[k].z);
            float e3 = __expf(-av[k].w * cn[k].w);
            top += mv[k].x * e0 + mv[k].y * e1 + mv[k].z * e2 + mv[k].w * e3;
            bot += sv[k].x * e0 + sv[k].y * e1 + sv[k].z * e2 + sv[k].w * e3;
        }
    } else {
        // type B: mask rows [128,512); ew[rr][j] = exp(-att[j][cr0+rr]*rinv[j])
        int tb = tile - 16;                       // 0..47
        int cr0 = tb * 8;
        const float4* a4 = (const float4*)(att + (size_t)b * N1_ * N2_);
        {
            int j = t >> 1, q = t & 1;
            float4 a = a4[j * 96 + tb * 2 + q];
            float rv = ws[RNI_OFF + b * N1_ + j];
            ew[(4 * q + 0) * EWS + j] = __expf(-a.x * rv);
            ew[(4 * q + 1) * EWS + j] = __expf(-a.y * rv);
            ew[(4 * q + 2) * EWS + j] = __expf(-a.z * rv);
            ew[(4 * q + 3) * EWS + j] = __expf(-a.w * rv);
        }
        const float4* m4 = (const float4*)(mapping + ((size_t)b * N_ + N1_ + cr0) * N_);
        const float4* s4 = (const float4*)(samelb + ((size_t)b * N_ + N1_ + cr0) * N_);
        float4 mL = ntl4(&m4[r * 128 + c4]);
        float4 sL = ntl4(&s4[r * 128 + c4]);
        float4 mR[3], sR[3];
        #pragma unroll
        for (int k = 0; k < 3; ++k) {
            int c = c4 + 32 * k;
            mR[k] = ntl4(&m4[r * 128 + 32 + c]);
            sR[k] = ntl4(&s4[r * 128 + 32 + c]);
        }
        __syncthreads();
        float4 w = *(const float4*)&ew[r * EWS + c4 * 4];
        top = mL.x * w.x + mL.y * w.y + mL.z * w.z + mL.w * w.w;
        bot = sL.x * w.x + sL.y * w.y + sL.z * w.z + sL.w * w.w;
        #pragma unroll
        for (int k = 0; k < 3; ++k) {
            top += mR[k].x + mR[k].y + mR[k].z + mR[k].w;
            bot += sR[k].x + sR[k].y + sR[k].z + sR[k].w;
        }
    }
    for (int off = 32; off > 0; off >>= 1) {
        top += __shfl_down(top, off, 64);
        bot += __shfl_down(bot, off, 64);
    }
    int wv = t >> 6, ln = t & 63;
    if (ln == 0) { rt[wv] = top; rb[wv] = bot; }
    __syncthreads();
    if (t == 0) {
        atomicAdd(&ws[ACC_TOP + b], rt[0] + rt[1] + rt[2] + rt[3]);
        atomicAdd(&ws[ACC_BOT + b], rb[0] + rb[1] + rb[2] + rb[3]);
    }
}

// ---------------- back: kabsch+pair+finalize (y==0) | scores MLP (y==1) ----------------
__device__ inline float bred(float* s2, float v, int t) {
    for (int off = 32; off > 0; off >>= 1) v += __shfl_down(v, off, 64);
    if ((t & 63) == 0) s2[t >> 6] = v;
    __syncthreads();
    float r = s2[0] + s2[1];
    __syncthreads();
    return r;
}

// grid (B, 2), block 128
__global__ void k_back(const float* __restrict__ coords, const float* __restrict__ upd,
                       const float* __restrict__ nm, const int* __restrict__ ei,
                       const float* __restrict__ W0, const float* __restrict__ b0,
                       const float* __restrict__ W1, const float* __restrict__ b1,
                       const float* __restrict__ W2, const float* __restrict__ b2,
                       const float* __restrict__ W3, const float* __restrict__ b3,
                       const float* __restrict__ ws, float* __restrict__ out) {
    __shared__ float sh[2 * DFC];
    int b = blockIdx.x, t = threadIdx.x;
    if (blockIdx.y == 1) {
        // ---- scores MLP ----
        float* pool = sh;           // 64
        float* h    = sh + 64;      // 128
        __shared__ float part[DFC];
        if (t < DIN) pool[t] = ws[POOL_OFF + b * DIN + t] * (1.0f / 128.0f);
        __syncthreads();
        float a = b0[t];
        #pragma unroll
        for (int i = 0; i < DIN; ++i) a += pool[i] * W0[i * DFC + t];
        float hv = fmaxf(a, 0.f);
        __syncthreads(); h[t] = hv; __syncthreads();
        a = b1[t];
        #pragma unroll
        for (int i = 0; i < DFC; ++i) a += h[i] * W1[i * DFC + t];
        hv = fmaxf(a, 0.f);
        __syncthreads(); h[t] = hv; __syncthreads();
        a = b2[t];
        #pragma unroll
        for (int i = 0; i < DFC; ++i) a += h[i] * W2[i * DFC + t];
        part[t] = fmaxf(a, 0.f) * W3[t];
        __syncthreads();
        for (int off = 64; off > 0; off >>= 1) { if (t < off) part[t] += part[t + off]; __syncthreads(); }
        if (t == 0) out[b] = 1.f / (1.f + expf(-(part[0] + b3[0])));
        return;
    }
    // ---- Kabsch ----
    float* s2 = sh;
    __shared__ float Rsh[9], Tsh[3];
    int bidx = ((const int*)ws)[BI_OFF + b * N1_ + t];
    float P[3], Q[3];
    const float* up = upd + ((size_t)b * N_ + t) * 3;
    P[0] = up[0]; P[1] = up[1]; P[2] = up[2];
    const float* qp = coords + ((size_t)b * N_ + N1_ + bidx) * 3;
    Q[0] = qp[0]; Q[1] = qp[1]; Q[2] = qp[2];
    float Pm[3], Qm[3];
    for (int a = 0; a < 3; ++a) Pm[a] = bred(s2, P[a], t) * (1.f / 128.f);
    for (int a = 0; a < 3; ++a) Qm[a] = bred(s2, Q[a], t) * (1.f / 128.f);
    float H[9];
    for (int a = 0; a < 3; ++a)
        for (int c = 0; c < 3; ++c)
            H[a * 3 + c] = bred(s2, (P[a] - Pm[a]) * (Q[c] - Qm[c]), t) * (1.f / 8.f);
    if (t == 0) {
        double Hd[3][3];
        for (int a = 0; a < 3; ++a) for (int c = 0; c < 3; ++c) Hd[a][c] = (double)H[a * 3 + c];
        double A[3][3], V[3][3] = {{1,0,0},{0,1,0},{0,0,1}};
        for (int i = 0; i < 3; ++i)
            for (int j = 0; j < 3; ++j) {
                double z = 0; for (int c = 0; c < 3; ++c) z += Hd[c][i] * Hd[c][j];
                A[i][j] = z;
            }
        for (int sweep = 0; sweep < 8; ++sweep) {
            const int PQ[3][2] = {{0,1},{0,2},{1,2}};
            for (int r = 0; r < 3; ++r) {
                int p = PQ[r][0], q = PQ[r][1];
                double apq = A[p][q];
                if (fabs(apq) < 1e-300) continue;
                double tau = (A[q][q] - A[p][p]) / (2.0 * apq);
                double tt = (tau >= 0 ? 1.0 : -1.0) / (fabs(tau) + sqrt(1.0 + tau * tau));
                double c = 1.0 / sqrt(1.0 + tt * tt), s = tt * c;
                for (int k = 0; k < 3; ++k) { double akp = A[k][p], akq = A[k][q]; A[k][p] = c * akp - s * akq; A[k][q] = s * akp + c * akq; }
                for (int k = 0; k < 3; ++k) { double apk = A[p][k], aqk = A[q][k]; A[p][k] = c * apk - s * aqk; A[q][k] = s * apk + c * aqk; }
                for (int k = 0; k < 3; ++k) { double vkp = V[k][p], vkq = V[k][q]; V[k][p] = c * vkp - s * vkq; V[k][q] = s * vkp + c * vkq; }
            }
        }
        double lam[3] = {A[0][0], A[1][1], A[2][2]};
        int id[3] = {0, 1, 2};
        if (lam[id[0]] < lam[id[1]]) { int x = id[0]; id[0] = id[1]; id[1] = x; }
        if (lam[id[0]] < lam[id[2]]) { int x = id[0]; id[0] = id[2]; id[2] = x; }
        if (lam[id[1]] < lam[id[2]]) { int x = id[1]; id[1] = id[2]; id[2] = x; }
        double u[3][3], v[3][3], sv[3];
        for (int i = 0; i < 3; ++i) {
            for (int k = 0; k < 3; ++k) v[i][k] = V[k][id[i]];
            double uv[3];
            for (int c = 0; c < 3; ++c) uv[c] = Hd[c][0] * v[i][0] + Hd[c][1] * v[i][1] + Hd[c][2] * v[i][2];
            double n = sqrt(uv[0] * uv[0] + uv[1] * uv[1] + uv[2] * uv[2]);
            sv[i] = n;
            if (n > 1e-150) { u[i][0] = uv[0] / n; u[i][1] = uv[1] / n; u[i][2] = uv[2] / n; }
            else { u[i][0] = u[i][1] = u[i][2] = 0.0; }
        }
        if (sv[2] < 1e-12 * fmax(sv[0], 1e-300)) {
            u[2][0] = u[0][1] * u[1][2] - u[0][2] * u[1][1];
            u[2][1] = u[0][2] * u[1][0] - u[0][0] * u[1][2];
            u[2][2] = u[0][0] * u[1][1] - u[0][1] * u[1][0];
        }
        double det = Hd[0][0] * (Hd[1][1] * Hd[2][2] - Hd[1][2] * Hd[2][1])
                   - Hd[0][1] * (Hd[1][0] * Hd[2][2] - Hd[1][2] * Hd[2][0])
                   + Hd[0][2] * (Hd[1][0] * Hd[2][1] - Hd[1][1] * Hd[2][0]);
        double dsg = (det > 0.0) ? 1.0 : ((det < 0.0) ? -1.0 : 0.0);
        for (int a = 0; a < 3; ++a)
            for (int c = 0; c < 3; ++c)
                Rsh[a * 3 + c] = (float)(u[0][a] * v[0][c] + u[1][a] * v[1][c] + dsg * u[2][a] * v[2][c]);
        for (int a = 0; a < 3; ++a)
            Tsh[a] = Qm[a] - (Rsh[a * 3] * Pm[0] + Rsh[a * 3 + 1] * Pm[1] + Rsh[a * 3 + 2] * Pm[2]);
    }
    __syncthreads();
    float Pp[3];
    for (int a = 0; a < 3; ++a)
        Pp[a] = Rsh[a * 3] * P[0] + Rsh[a * 3 + 1] * P[1] + Rsh[a * 3 + 2] * P[2] + Tsh[a];
    float mk = (nm[b * N1_ + t] > 0.5f) ? 1.f : 0.f;
    float dx = Pp[0] - Q[0], dy = Pp[1] - Q[1], dz = Pp[2] - Q[2];
    float rsum = bred(s2, mk * (dx * dx + dy * dy + dz * dz), t);
    float msum = bred(s2, mk, t);
    float Ppm[3];
    for (int a = 0; a < 3; ++a) Ppm[a] = bred(s2, Pp[a], t) * (1.f / 128.f);
    if (t == 0) {
        float cnt = fmaxf(msum * 3.f, 1.f);
        atomicAdd(&out[129], (rsum / cnt) * (1.f / 128.f));
        float cen = 0.f;
        for (int a = 0; a < 3; ++a) { float d2 = Ppm[a] - Qm[a]; cen += d2 * d2; }
        atomicAdd(&out[131], (cen / 3.f) * (1.f / 128.f));
    }
    // ---- fused pairdst ----
    const float* C = coords + (size_t)b * N_ * 3;
    const float* U = upd + (size_t)b * N_ * 3;
    const int* e = ei + (size_t)b * E_ * 2;
    float acc = 0.f;
    for (int idx = t; idx < E_; idx += 128) {
        int a0 = e[idx * 2], a1 = e[idx * 2 + 1];
        float ex = C[a0 * 3] - C[a1 * 3], ey = C[a0 * 3 + 1] - C[a1 * 3 + 1], ez = C[a0 * 3 + 2] - C[a1 * 3 + 2];
        float d0 = sqrtf(ex * ex + ey * ey + ez * ez + 1e-12f);
        ex = U[a0 * 3] - U[a1 * 3]; ey = U[a0 * 3 + 1] - U[a1 * 3 + 1]; ez = U[a0 * 3 + 2] - U[a1 * 3 + 2];
        float d1 = sqrtf(ex * ex + ey * ey + ez * ez + 1e-12f);
        acc += d1 - d0;
    }
    float psum = bred(s2, acc, t);
    if (t == 0) atomicAdd(&out[130], fabsf(psum) * (1.f / 128.f));
    // ---- attn_loss finalize ----
    if (b == 0) {
        float top = ws[ACC_TOP + t], bot = ws[ACC_BOT + t];
        float v = top / (bot - top + 1.0f);
        float s = bred(s2, v, t);
        if (t == 0) out[128] = s * (1.0f / 128.0f);
    }
}

extern "C" void kernel_launch(void* const* d_in, const int* in_sizes, int n_in,
                              void* d_out, int out_size, void* d_ws, size_t ws_size,
                              hipStream_t stream) {
    const float* c_hs      = (const float*)d_in[0];
    const float* attention = (const float*)d_in[1];
    const float* coords    = (const float*)d_in[2];
    const float* upd       = (const float*)d_in[3];
    const float* c_valid   = (const float*)d_in[4];
    const float* nm        = (const float*)d_in[5];
    const float* mapping   = (const float*)d_in[6];
    const float* samelb    = (const float*)d_in[7];
    const int*   ei        = (const int*)d_in[8];
    const float* W0 = (const float*)d_in[9],  *b0 = (const float*)d_in[10];
    const float* W1 = (const float*)d_in[11], *b1 = (const float*)d_in[12];
    const float* W2 = (const float*)d_in[13], *b2 = (const float*)d_in[14];
    const float* W3 = (const float*)d_in[15], *b3 = (const float*)d_in[16];
    float* out = (float*)d_out;
    float* ws  = (float*)d_ws;

    hipLaunchKernelGGL(k_pre,  dim3(B_, 2), dim3(512), 0, stream, c_hs, c_valid, attention, ws, out);
    hipLaunchKernelGGL(k_scan, dim3(8192),  dim3(256), 0, stream, attention, mapping, samelb, ws);
    hipLaunchKernelGGL(k_back, dim3(B_, 2), dim3(128), 0, stream, coords, upd, nm, ei,
                       W0, b0, W1, b1, W2, b2, W3, b3, ws, out);
}

// Round 6
// 343.671 us; speedup vs baseline: 1.1339x; 1.0189x over previous
//
#include <hip/hip_runtime.h>
#include <math.h>

#define B_   128
#define N1_  128
#define N2_  384
#define N_   512
#define E_   1024
#define DIN  64
#define DFC  128

// workspace layout (floats)
#define ACC_TOP  0
#define ACC_BOT  128
#define POOL_OFF 256                          // B*64 = 8192
#define RNI_OFF  (POOL_OFF + B_*DIN)          // 8448:  B*N1 reciprocal rownorms
#define BI_OFF   (RNI_OFF + B_*N1_)           // 24832: B*N1 argmax ints
#define CNI_OFF  (BI_OFF + B_*N1_)            // 41216: B*N2 reciprocal colnorms

// nontemporal float4 load (native ext_vector type required by the builtin)
typedef float f4v __attribute__((ext_vector_type(4)));
__device__ __forceinline__ float4 ntl4(const float4* p) {
    f4v v = __builtin_nontemporal_load((const f4v*)p);
    float4 r; r.x = v.x; r.y = v.y; r.z = v.z; r.w = v.w;
    return r;
}

// ---------------- pre: pool (y==0) | att stats rownorm+argmax+colnorm (y==1) ----------------
// grid (B, 2), block 512 (8 waves/CU for latency hiding).
// One block per batch per role -> no global atomics, no init pass.
// Linear block id = b + 128*y, 128%8==0 -> batch b always on XCD b&7 (matches k_scan decode).
__global__ void k_pre(const float* __restrict__ c_hs, const float* __restrict__ c_valid,
                      const float* __restrict__ att, float* __restrict__ ws,
                      float* __restrict__ out) {
    __shared__ float4 sred4[512];        // pool reduce (8 KB)
    __shared__ float colp[16][N2_];      // att col-ssq partials (24 KB)
    int b = blockIdx.x, t = threadIdx.x;
    if (blockIdx.y == 0) {
        // zero the cross-kernel accumulators (k_scan / k_back add into these later)
        if (t == 0) { ws[ACC_TOP + b] = 0.f; ws[ACC_BOT + b] = 0.f; }
        if (b == 0 && t < 4) out[128 + t] = 0.f;
        // masked mean-pool over all 512 rows (c_hs single-use -> nontemporal)
        int d4 = t & 15, rl = t >> 4;            // rl: 0..31
        const float4* X4 = (const float4*)(c_hs + (size_t)b * N_ * DIN);
        const float* V = c_valid + (size_t)b * N_;
        float4 acc = {0.f, 0.f, 0.f, 0.f};
        for (int r = rl; r < N_; r += 32) {
            float4 x = ntl4(&X4[r * 16 + d4]);
            float v = V[r];
            acc.x += x.x * v; acc.y += x.y * v; acc.z += x.z * v; acc.w += x.w * v;
        }
        sred4[t] = acc; __syncthreads();
        for (int off = 256; off >= 16; off >>= 1) {
            if (t < off) {
                float4 o = sred4[t + off];
                sred4[t].x += o.x; sred4[t].y += o.y; sred4[t].z += o.z; sred4[t].w += o.w;
            }
            __syncthreads();
        }
        if (t < 16) {
            float4 s = sred4[t];
            float* p = ws + POOL_OFF + b * DIN + t * 4;
            p[0] = s.x; p[1] = s.y; p[2] = s.z; p[3] = s.w;
        }
        return;
    }
    // ---- y==1: att stats. 16 row-groups x 32 lanes; regular loads keep att warm in this XCD's L2
    int lane = t & 31, grp = t >> 5;             // grp: 0..15
    const float4* a4 = (const float4*)(att + (size_t)b * N1_ * N2_);
    float4 cs[3] = {{0,0,0,0},{0,0,0,0},{0,0,0,0}};
    for (int rr = 0; rr < N1_; rr += 16) {
        int r = rr + grp;
        float ssq = 0.f, best = -1e30f; int bidx = 0;
        #pragma unroll
        for (int c = 0; c < 3; ++c) {
            float4 v = a4[(size_t)r * 96 + c * 32 + lane];
            cs[c].x += v.x * v.x; cs[c].y += v.y * v.y;
            cs[c].z += v.z * v.z; cs[c].w += v.w * v.w;
            ssq += v.x * v.x + v.y * v.y + v.z * v.z + v.w * v.w;
            int cb = (c * 32 + lane) * 4;        // ascending within thread
            if (v.x > best) { best = v.x; bidx = cb; }
            if (v.y > best) { best = v.y; bidx = cb + 1; }
            if (v.z > best) { best = v.z; bidx = cb + 2; }
            if (v.w > best) { best = v.w; bidx = cb + 3; }
        }
        // reduce across the 32-lane row group (xor<=16 stays within the 32-lane half-wave)
        for (int off = 16; off > 0; off >>= 1) {
            ssq += __shfl_xor(ssq, off, 64);
            float ov = __shfl_xor(best, off, 64);
            int oi = __shfl_xor(bidx, off, 64);
            if (ov > best || (ov == best && oi < bidx)) { best = ov; bidx = oi; }
        }
        if (lane == 0) {
            ws[RNI_OFF + b * N1_ + r] = 1.f / fmaxf(sqrtf(ssq), 1e-12f);
            ((int*)ws)[BI_OFF + b * N1_ + r] = bidx;
        }
    }
    #pragma unroll
    for (int c = 0; c < 3; ++c) {
        int fc = (c * 32 + lane) * 4;
        colp[grp][fc]     = cs[c].x;
        colp[grp][fc + 1] = cs[c].y;
        colp[grp][fc + 2] = cs[c].z;
        colp[grp][fc + 3] = cs[c].w;
    }
    __syncthreads();
    for (int cc = t; cc < N2_; cc += 512) {
        float s = 0.f;
        #pragma unroll
        for (int g = 0; g < 16; ++g) s += colp[g][cc];
        ws[CNI_OFF + b * N2_ + cc] = 1.f / fmaxf(sqrtf(s), 1e-12f);
    }
}

// ---------------- fused mask scan ----------------
// flat grid 8192, block 256, 8 blocks/CU (32 waves -> max outstanding NT loads).
// XCD decode: batch b = xcd + 8*q  ->  b&7 == xcd, matching k_pre's placement (warm att in L2).
// mask streams nontemporal (single-use); att/cninv/rinv L2-resident.
#define EWS 132
__global__ __launch_bounds__(256, 8)
void k_scan(const float* __restrict__ att, const float* __restrict__ mapping,
            const float* __restrict__ samelb, float* __restrict__ ws) {
    __shared__ float ew[8 * EWS];
    __shared__ float rt[4], rb[4];
    int d = blockIdx.x;
    int xcd = d & 7, kk = d >> 3;
    int b = xcd + 8 * (kk >> 6);                  // batch -> XCD b&7
    int tile = kk & 63;                           // 0..63 within batch
    int t = threadIdx.x;
    float top = 0.f, bot = 0.f;
    int r = t >> 5, c4 = t & 31;                  // r: 0..7 row-in-tile, c4: float4 col
    if (tile < 16) {
        // type A: mask rows [0,128): cols<128 count; cols>=128 exp(-att*cninv)
        int i0 = tile * 8;
        const float4* m4 = (const float4*)(mapping + ((size_t)b * N_ + i0) * N_);
        const float4* s4 = (const float4*)(samelb + ((size_t)b * N_ + i0) * N_);
        const float4* a4 = (const float4*)(att + ((size_t)b * N1_ + i0) * N2_);
        const float4* cn4 = (const float4*)(ws + CNI_OFF + (size_t)b * N2_);
        float4 md = ntl4(&m4[r * 128 + c4]);
        float4 sd = ntl4(&s4[r * 128 + c4]);
        float4 av[3], mv[3], sv[3], cn[3];
        #pragma unroll
        for (int k = 0; k < 3; ++k) {
            int c = c4 + 32 * k;
            av[k] = a4[r * 96 + c];
            mv[k] = ntl4(&m4[r * 128 + 32 + c]);
            sv[k] = ntl4(&s4[r * 128 + 32 + c]);
            cn[k] = cn4[c];
        }
        top = md.x + md.y + md.z + md.w;
        bot = sd.x + sd.y + sd.z + sd.w;
        #pragma unroll
        for (int k = 0; k < 3; ++k) {
            float e0 = __expf(-av[k].x * cn[k].x);
            float e1 = __expf(-av[k].y * cn[k].y);
            float e2 = __expf(-av[k].z * cn[k].z);
            float e3 = __expf(-av[k].w * cn[k].w);
            top += mv[k].x * e0 + mv[k].y * e1 + mv[k].z * e2 + mv[k].w * e3;
            bot += sv[k].x * e0 + sv[k].y * e1 + sv[k].z * e2 + sv[k].w * e3;
        }
    } else {
        // type B: mask rows [128,512); ew[rr][j] = exp(-att[j][cr0+rr]*rinv[j])
        int tb = tile - 16;                       // 0..47
        int cr0 = tb * 8;
        const float4* a4 = (const float4*)(att + (size_t)b * N1_ * N2_);
        {
            int j = t >> 1, q = t & 1;
            float4 a = a4[j * 96 + tb * 2 + q];
            float rv = ws[RNI_OFF + b * N1_ + j];
            ew[(4 * q + 0) * EWS + j] = __expf(-a.x * rv);
            ew[(4 * q + 1) * EWS + j] = __expf(-a.y * rv);
            ew[(4 * q + 2) * EWS + j] = __expf(-a.z * rv);
            ew[(4 * q + 3) * EWS + j] = __expf(-a.w * rv);
        }
        const float4* m4 = (const float4*)(mapping + ((size_t)b * N_ + N1_ + cr0) * N_);
        const float4* s4 = (const float4*)(samelb + ((size_t)b * N_ + N1_ + cr0) * N_);
        float4 mL = ntl4(&m4[r * 128 + c4]);
        float4 sL = ntl4(&s4[r * 128 + c4]);
        float4 mR[3], sR[3];
        #pragma unroll
        for (int k = 0; k < 3; ++k) {
            int c = c4 + 32 * k;
            mR[k] = ntl4(&m4[r * 128 + 32 + c]);
            sR[k] = ntl4(&s4[r * 128 + 32 + c]);
        }
        __syncthreads();
        float4 w = *(const float4*)&ew[r * EWS + c4 * 4];
        top = mL.x * w.x + mL.y * w.y + mL.z * w.z + mL.w * w.w;
        bot = sL.x * w.x + sL.y * w.y + sL.z * w.z + sL.w * w.w;
        #pragma unroll
        for (int k = 0; k < 3; ++k) {
            top += mR[k].x + mR[k].y + mR[k].z + mR[k].w;
            bot += sR[k].x + sR[k].y + sR[k].z + sR[k].w;
        }
    }
    for (int off = 32; off > 0; off >>= 1) {
        top += __shfl_down(top, off, 64);
        bot += __shfl_down(bot, off, 64);
    }
    int wv = t >> 6, ln = t & 63;
    if (ln == 0) { rt[wv] = top; rb[wv] = bot; }
    __syncthreads();
    if (t == 0) {
        atomicAdd(&ws[ACC_TOP + b], rt[0] + rt[1] + rt[2] + rt[3]);
        atomicAdd(&ws[ACC_BOT + b], rb[0] + rb[1] + rb[2] + rb[3]);
    }
}

// ---------------- back: kabsch+finalize (y==0) | scores MLP (y==1) | pairdst (y==2) ----------
__device__ inline float bred(float* s2, float v, int t) {
    for (int off = 32; off > 0; off >>= 1) v += __shfl_down(v, off, 64);
    if ((t & 63) == 0) s2[t >> 6] = v;
    __syncthreads();
    float r = s2[0] + s2[1];
    __syncthreads();
    return r;
}

// grid (B, 3), block 128
__global__ void k_back(const float* __restrict__ coords, const float* __restrict__ upd,
                       const float* __restrict__ nm, const int* __restrict__ ei,
                       const float* __restrict__ W0, const float* __restrict__ b0,
                       const float* __restrict__ W1, const float* __restrict__ b1,
                       const float* __restrict__ W2, const float* __restrict__ b2,
                       const float* __restrict__ W3, const float* __restrict__ b3,
                       const float* __restrict__ ws, float* __restrict__ out) {
    __shared__ float sh[2 * DFC];
    int b = blockIdx.x, t = threadIdx.x;
    if (blockIdx.y == 2) {
        // ---- pairdst (independent; overlaps Kabsch blocks) ----
        float* s2 = sh;
        const float* C = coords + (size_t)b * N_ * 3;
        const float* U = upd + (size_t)b * N_ * 3;
        const int* e = ei + (size_t)b * E_ * 2;
        float acc = 0.f;
        for (int idx = t; idx < E_; idx += 128) {
            int a0 = e[idx * 2], a1 = e[idx * 2 + 1];
            float ex = C[a0 * 3] - C[a1 * 3], ey = C[a0 * 3 + 1] - C[a1 * 3 + 1], ez = C[a0 * 3 + 2] - C[a1 * 3 + 2];
            float d0 = sqrtf(ex * ex + ey * ey + ez * ez + 1e-12f);
            ex = U[a0 * 3] - U[a1 * 3]; ey = U[a0 * 3 + 1] - U[a1 * 3 + 1]; ez = U[a0 * 3 + 2] - U[a1 * 3 + 2];
            float d1 = sqrtf(ex * ex + ey * ey + ez * ez + 1e-12f);
            acc += d1 - d0;
        }
        float psum = bred(s2, acc, t);
        if (t == 0) atomicAdd(&out[130], fabsf(psum) * (1.f / 128.f));
        return;
    }
    if (blockIdx.y == 1) {
        // ---- scores MLP ----
        float* pool = sh;           // 64
        float* h    = sh + 64;      // 128
        __shared__ float part[DFC];
        if (t < DIN) pool[t] = ws[POOL_OFF + b * DIN + t] * (1.0f / 128.0f);
        __syncthreads();
        float a = b0[t];
        #pragma unroll
        for (int i = 0; i < DIN; ++i) a += pool[i] * W0[i * DFC + t];
        float hv = fmaxf(a, 0.f);
        __syncthreads(); h[t] = hv; __syncthreads();
        a = b1[t];
        #pragma unroll
        for (int i = 0; i < DFC; ++i) a += h[i] * W1[i * DFC + t];
        hv = fmaxf(a, 0.f);
        __syncthreads(); h[t] = hv; __syncthreads();
        a = b2[t];
        #pragma unroll
        for (int i = 0; i < DFC; ++i) a += h[i] * W2[i * DFC + t];
        part[t] = fmaxf(a, 0.f) * W3[t];
        __syncthreads();
        for (int off = 64; off > 0; off >>= 1) { if (t < off) part[t] += part[t + off]; __syncthreads(); }
        if (t == 0) out[b] = 1.f / (1.f + expf(-(part[0] + b3[0])));
        return;
    }
    // ---- Kabsch ----
    float* s2 = sh;
    __shared__ float Rsh[9], Tsh[3];
    int bidx = ((const int*)ws)[BI_OFF + b * N1_ + t];
    float P[3], Q[3];
    const float* up = upd + ((size_t)b * N_ + t) * 3;
    P[0] = up[0]; P[1] = up[1]; P[2] = up[2];
    const float* qp = coords + ((size_t)b * N_ + N1_ + bidx) * 3;
    Q[0] = qp[0]; Q[1] = qp[1]; Q[2] = qp[2];
    float Pm[3], Qm[3];
    for (int a = 0; a < 3; ++a) Pm[a] = bred(s2, P[a], t) * (1.f / 128.f);
    for (int a = 0; a < 3; ++a) Qm[a] = bred(s2, Q[a], t) * (1.f / 128.f);
    float H[9];
    for (int a = 0; a < 3; ++a)
        for (int c = 0; c < 3; ++c)
            H[a * 3 + c] = bred(s2, (P[a] - Pm[a]) * (Q[c] - Qm[c]), t) * (1.f / 8.f);
    if (t == 0) {
        double Hd[3][3];
        for (int a = 0; a < 3; ++a) for (int c = 0; c < 3; ++c) Hd[a][c] = (double)H[a * 3 + c];
        double A[3][3], V[3][3] = {{1,0,0},{0,1,0},{0,0,1}};
        for (int i = 0; i < 3; ++i)
            for (int j = 0; j < 3; ++j) {
                double z = 0; for (int c = 0; c < 3; ++c) z += Hd[c][i] * Hd[c][j];
                A[i][j] = z;
            }
        for (int sweep = 0; sweep < 8; ++sweep) {
            const int PQ[3][2] = {{0,1},{0,2},{1,2}};
            for (int r = 0; r < 3; ++r) {
                int p = PQ[r][0], q = PQ[r][1];
                double apq = A[p][q];
                if (fabs(apq) < 1e-300) continue;
                double tau = (A[q][q] - A[p][p]) / (2.0 * apq);
                double tt = (tau >= 0 ? 1.0 : -1.0) / (fabs(tau) + sqrt(1.0 + tau * tau));
                double c = 1.0 / sqrt(1.0 + tt * tt), s = tt * c;
                for (int k = 0; k < 3; ++k) { double akp = A[k][p], akq = A[k][q]; A[k][p] = c * akp - s * akq; A[k][q] = s * akp + c * akq; }
                for (int k = 0; k < 3; ++k) { double apk = A[p][k], aqk = A[q][k]; A[p][k] = c * apk - s * aqk; A[q][k] = s * apk + c * aqk; }
                for (int k = 0; k < 3; ++k) { double vkp = V[k][p], vkq = V[k][q]; V[k][p] = c * vkp - s * vkq; V[k][q] = s * vkp + c * vkq; }
            }
        }
        double lam[3] = {A[0][0], A[1][1], A[2][2]};
        int id[3] = {0, 1, 2};
        if (lam[id[0]] < lam[id[1]]) { int x = id[0]; id[0] = id[1]; id[1] = x; }
        if (lam[id[0]] < lam[id[2]]) { int x = id[0]; id[0] = id[2]; id[2] = x; }
        if (lam[id[1]] < lam[id[2]]) { int x = id[1]; id[1] = id[2]; id[2] = x; }
        double u[3][3], v[3][3], sv[3];
        for (int i = 0; i < 3; ++i) {
            for (int k = 0; k < 3; ++k) v[i][k] = V[k][id[i]];
            double uv[3];
            for (int c = 0; c < 3; ++c) uv[c] = Hd[c][0] * v[i][0] + Hd[c][1] * v[i][1] + Hd[c][2] * v[i][2];
            double n = sqrt(uv[0] * uv[0] + uv[1] * uv[1] + uv[2] * uv[2]);
            sv[i] = n;
            if (n > 1e-150) { u[i][0] = uv[0] / n; u[i][1] = uv[1] / n; u[i][2] = uv[2] / n; }
            else { u[i][0] = u[i][1] = u[i][2] = 0.0; }
        }
        if (sv[2] < 1e-12 * fmax(sv[0], 1e-300)) {
            u[2][0] = u[0][1] * u[1][2] - u[0][2] * u[1][1];
            u[2][1] = u[0][2] * u[1][0] - u[0][0] * u[1][2];
            u[2][2] = u[0][0] * u[1][1] - u[0][1] * u[1][0];
        }
        double det = Hd[0][0] * (Hd[1][1] * Hd[2][2] - Hd[1][2] * Hd[2][1])
                   - Hd[0][1] * (Hd[1][0] * Hd[2][2] - Hd[1][2] * Hd[2][0])
                   + Hd[0][2] * (Hd[1][0] * Hd[2][1] - Hd[1][1] * Hd[2][0]);
        double dsg = (det > 0.0) ? 1.0 : ((det < 0.0) ? -1.0 : 0.0);
        for (int a = 0; a < 3; ++a)
            for (int c = 0; c < 3; ++c)
                Rsh[a * 3 + c] = (float)(u[0][a] * v[0][c] + u[1][a] * v[1][c] + dsg * u[2][a] * v[2][c]);
        for (int a = 0; a < 3; ++a)
            Tsh[a] = Qm[a] - (Rsh[a * 3] * Pm[0] + Rsh[a * 3 + 1] * Pm[1] + Rsh[a * 3 + 2] * Pm[2]);
    }
    __syncthreads();
    float Pp[3];
    for (int a = 0; a < 3; ++a)
        Pp[a] = Rsh[a * 3] * P[0] + Rsh[a * 3 + 1] * P[1] + Rsh[a * 3 + 2] * P[2] + Tsh[a];
    float mk = (nm[b * N1_ + t] > 0.5f) ? 1.f : 0.f;
    float dx = Pp[0] - Q[0], dy = Pp[1] - Q[1], dz = Pp[2] - Q[2];
    float rsum = bred(s2, mk * (dx * dx + dy * dy + dz * dz), t);
    float msum = bred(s2, mk, t);
    float Ppm[3];
    for (int a = 0; a < 3; ++a) Ppm[a] = bred(s2, Pp[a], t) * (1.f / 128.f);
    if (t == 0) {
        float cnt = fmaxf(msum * 3.f, 1.f);
        atomicAdd(&out[129], (rsum / cnt) * (1.f / 128.f));
        float cen = 0.f;
        for (int a = 0; a < 3; ++a) { float d2 = Ppm[a] - Qm[a]; cen += d2 * d2; }
        atomicAdd(&out[131], (cen / 3.f) * (1.f / 128.f));
    }
    // ---- attn_loss finalize ----
    if (b == 0) {
        float top = ws[ACC_TOP + t], bot = ws[ACC_BOT + t];
        float v = top / (bot - top + 1.0f);
        float s = bred(s2, v, t);
        if (t == 0) out[128] = s * (1.0f / 128.0f);
    }
}

extern "C" void kernel_launch(void* const* d_in, const int* in_sizes, int n_in,
                              void* d_out, int out_size, void* d_ws, size_t ws_size,
                              hipStream_t stream) {
    const float* c_hs      = (const float*)d_in[0];
    const float* attention = (const float*)d_in[1];
    const float* coords    = (const float*)d_in[2];
    const float* upd       = (const float*)d_in[3];
    const float* c_valid   = (const float*)d_in[4];
    const float* nm        = (const float*)d_in[5];
    const float* mapping   = (const float*)d_in[6];
    const float* samelb    = (const float*)d_in[7];
    const int*   ei        = (const int*)d_in[8];
    const float* W0 = (const float*)d_in[9],  *b0 = (const float*)d_in[10];
    const float* W1 = (const float*)d_in[11], *b1 = (const float*)d_in[12];
    const float* W2 = (const float*)d_in[13], *b2 = (const float*)d_in[14];
    const float* W3 = (const float*)d_in[15], *b3 = (const float*)d_in[16];
    float* out = (float*)d_out;
    float* ws  = (float*)d_ws;

    hipLaunchKernelGGL(k_pre,  dim3(B_, 2), dim3(512), 0, stream, c_hs, c_valid, attention, ws, out);
    hipLaunchKernelGGL(k_scan, dim3(8192),  dim3(256), 0, stream, attention, mapping, samelb, ws);
    hipLaunchKernelGGL(k_back, dim3(B_, 3), dim3(128), 0, stream, coords, upd, nm, ei,
                       W0, b0, W1, b1, W2, b2, W3, b3, ws, out);
}

// Round 7
// 343.276 us; speedup vs baseline: 1.1352x; 1.0012x over previous
//
#include <hip/hip_runtime.h>
#include <math.h>

#define B_   128
#define N1_  128
#define N2_  384
#define N_   512
#define E_   1024
#define DIN  64
#define DFC  128

// workspace layout (floats)
#define ACC_TOP  0
#define ACC_BOT  128
#define POOL_OFF 256                          // B*64 = 8192
#define RNI_OFF  (POOL_OFF + B_*DIN)          // 8448:  B*N1 reciprocal rownorms
#define BI_OFF   (RNI_OFF + B_*N1_)           // 24832: B*N1 argmax ints
#define CNI_OFF  (BI_OFF + B_*N1_)            // 41216: B*N2 reciprocal colnorms

// nontemporal float4 load (native ext_vector type required by the builtin)
typedef float f4v __attribute__((ext_vector_type(4)));
__device__ __forceinline__ float4 ntl4(const float4* p) {
    f4v v = __builtin_nontemporal_load((const f4v*)p);
    float4 r; r.x = v.x; r.y = v.y; r.z = v.z; r.w = v.w;
    return r;
}

// ---------------- pre: pool (y==0) | att stats rownorm+argmax+colnorm (y==1) ----------------
// grid (B, 2), block 512 (8 waves/CU for latency hiding).
// One block per batch per role -> no global atomics, no init pass.
// Linear block id = b + 128*y, 128%8==0 -> batch b always on XCD b&7 (matches k_scan decode).
__global__ void k_pre(const float* __restrict__ c_hs, const float* __restrict__ c_valid,
                      const float* __restrict__ att, float* __restrict__ ws,
                      float* __restrict__ out) {
    __shared__ float4 sred4[512];        // pool reduce (8 KB)
    __shared__ float colp[16][N2_];      // att col-ssq partials (24 KB)
    int b = blockIdx.x, t = threadIdx.x;
    if (blockIdx.y == 0) {
        // zero the cross-kernel accumulators (k_scan / k_back add into these later)
        if (t == 0) { ws[ACC_TOP + b] = 0.f; ws[ACC_BOT + b] = 0.f; }
        if (b == 0 && t < 4) out[128 + t] = 0.f;
        // masked mean-pool over all 512 rows (c_hs single-use -> nontemporal)
        int d4 = t & 15, rl = t >> 4;            // rl: 0..31
        const float4* X4 = (const float4*)(c_hs + (size_t)b * N_ * DIN);
        const float* V = c_valid + (size_t)b * N_;
        float4 acc = {0.f, 0.f, 0.f, 0.f};
        for (int r = rl; r < N_; r += 32) {
            float4 x = ntl4(&X4[r * 16 + d4]);
            float v = V[r];
            acc.x += x.x * v; acc.y += x.y * v; acc.z += x.z * v; acc.w += x.w * v;
        }
        sred4[t] = acc; __syncthreads();
        for (int off = 256; off >= 16; off >>= 1) {
            if (t < off) {
                float4 o = sred4[t + off];
                sred4[t].x += o.x; sred4[t].y += o.y; sred4[t].z += o.z; sred4[t].w += o.w;
            }
            __syncthreads();
        }
        if (t < 16) {
            float4 s = sred4[t];
            float* p = ws + POOL_OFF + b * DIN + t * 4;
            p[0] = s.x; p[1] = s.y; p[2] = s.z; p[3] = s.w;
        }
        return;
    }
    // ---- y==1: att stats. 16 row-groups x 32 lanes; regular loads keep att warm in this XCD's L2
    int lane = t & 31, grp = t >> 5;             // grp: 0..15
    const float4* a4 = (const float4*)(att + (size_t)b * N1_ * N2_);
    float4 cs[3] = {{0,0,0,0},{0,0,0,0},{0,0,0,0}};
    for (int rr = 0; rr < N1_; rr += 16) {
        int r = rr + grp;
        float ssq = 0.f, best = -1e30f; int bidx = 0;
        #pragma unroll
        for (int c = 0; c < 3; ++c) {
            float4 v = a4[(size_t)r * 96 + c * 32 + lane];
            cs[c].x += v.x * v.x; cs[c].y += v.y * v.y;
            cs[c].z += v.z * v.z; cs[c].w += v.w * v.w;
            ssq += v.x * v.x + v.y * v.y + v.z * v.z + v.w * v.w;
            int cb = (c * 32 + lane) * 4;        // ascending within thread
            if (v.x > best) { best = v.x; bidx = cb; }
            if (v.y > best) { best = v.y; bidx = cb + 1; }
            if (v.z > best) { best = v.z; bidx = cb + 2; }
            if (v.w > best) { best = v.w; bidx = cb + 3; }
        }
        // reduce across the 32-lane row group (xor<=16 stays within the 32-lane half-wave)
        for (int off = 16; off > 0; off >>= 1) {
            ssq += __shfl_xor(ssq, off, 64);
            float ov = __shfl_xor(best, off, 64);
            int oi = __shfl_xor(bidx, off, 64);
            if (ov > best || (ov == best && oi < bidx)) { best = ov; bidx = oi; }
        }
        if (lane == 0) {
            ws[RNI_OFF + b * N1_ + r] = 1.f / fmaxf(sqrtf(ssq), 1e-12f);
            ((int*)ws)[BI_OFF + b * N1_ + r] = bidx;
        }
    }
    #pragma unroll
    for (int c = 0; c < 3; ++c) {
        int fc = (c * 32 + lane) * 4;
        colp[grp][fc]     = cs[c].x;
        colp[grp][fc + 1] = cs[c].y;
        colp[grp][fc + 2] = cs[c].z;
        colp[grp][fc + 3] = cs[c].w;
    }
    __syncthreads();
    for (int cc = t; cc < N2_; cc += 512) {
        float s = 0.f;
        #pragma unroll
        for (int g = 0; g < 16; ++g) s += colp[g][cc];
        ws[CNI_OFF + b * N2_ + cc] = 1.f / fmaxf(sqrtf(s), 1e-12f);
    }
}

// ---------------- fused mask scan ----------------
// flat grid 2048 (= 8 blocks/CU exactly, one dispatch generation), block 256.
// Each block owns 4 same-type tiles of one batch: uniform values (cninv/rinv) hoisted,
// top/bot accumulate in registers across tiles -> 1 reduce + 1 atomic pair per block.
// XCD decode: batch b = xcd + 8*q  ->  b&7 == xcd, matching k_pre's placement (warm att in L2).
// mask streams nontemporal (single-use); att/cninv/rinv L2-resident.
#define EWS 132
__global__ __launch_bounds__(256, 8)
void k_scan(const float* __restrict__ att, const float* __restrict__ mapping,
            const float* __restrict__ samelb, float* __restrict__ ws) {
    __shared__ float ew[2][8 * EWS];              // double-buffered transpose tile
    __shared__ float rt[4], rb[4];
    int d = blockIdx.x;
    int xcd = d & 7, kk = d >> 3;                 // kk: 0..255
    int b = xcd + 8 * (kk >> 4);                  // batch -> XCD b&7
    int sub = kk & 15;                            // 0..15 within batch: 0..3 A-blocks, 4..15 B-blocks
    int t = threadIdx.x;
    float top = 0.f, bot = 0.f;
    int r = t >> 5, c4 = t & 31;                  // r: 0..7 row-in-tile, c4: float4 col
    if (sub < 4) {
        // type A: mask rows [sub*32, sub*32+32) in four 8-row tiles.
        // cols<128 count; cols>=128 exp(-att*cninv)
        const float4* cn4 = (const float4*)(ws + CNI_OFF + (size_t)b * N2_);
        float4 cn[3];
        #pragma unroll
        for (int k = 0; k < 3; ++k) cn[k] = cn4[c4 + 32 * k];   // hoisted: same cols every tile
        for (int it = 0; it < 4; ++it) {
            int i0 = (sub * 4 + it) * 8;
            const float4* m4 = (const float4*)(mapping + ((size_t)b * N_ + i0) * N_);
            const float4* s4 = (const float4*)(samelb + ((size_t)b * N_ + i0) * N_);
            const float4* a4 = (const float4*)(att + ((size_t)b * N1_ + i0) * N2_);
            float4 md = ntl4(&m4[r * 128 + c4]);
            float4 sd = ntl4(&s4[r * 128 + c4]);
            float4 av[3], mv[3], sv[3];
            #pragma unroll
            for (int k = 0; k < 3; ++k) {
                int c = c4 + 32 * k;
                av[k] = a4[r * 96 + c];
                mv[k] = ntl4(&m4[r * 128 + 32 + c]);
                sv[k] = ntl4(&s4[r * 128 + 32 + c]);
            }
            top += md.x + md.y + md.z + md.w;
            bot += sd.x + sd.y + sd.z + sd.w;
            #pragma unroll
            for (int k = 0; k < 3; ++k) {
                float e0 = __expf(-av[k].x * cn[k].x);
                float e1 = __expf(-av[k].y * cn[k].y);
                float e2 = __expf(-av[k].z * cn[k].z);
                float e3 = __expf(-av[k].w * cn[k].w);
                top += mv[k].x * e0 + mv[k].y * e1 + mv[k].z * e2 + mv[k].w * e3;
                bot += sv[k].x * e0 + sv[k].y * e1 + sv[k].z * e2 + sv[k].w * e3;
            }
        }
    } else {
        // type B: four 8-col tiles; ew[rr][j] = exp(-att[j][cr0+rr]*rinv[j])
        int tb0 = (sub - 4) * 4;                  // 0..44 step 4
        int j = t >> 1, q = t & 1;
        const float4* a4 = (const float4*)(att + (size_t)b * N1_ * N2_);
        float rv = ws[RNI_OFF + b * N1_ + j];     // hoisted: same row every tile
        for (int it = 0; it < 4; ++it) {
            int tb = tb0 + it;
            int cr0 = tb * 8;
            float* e = ew[it & 1];
            {
                float4 a = a4[j * 96 + tb * 2 + q];
                e[(4 * q + 0) * EWS + j] = __expf(-a.x * rv);
                e[(4 * q + 1) * EWS + j] = __expf(-a.y * rv);
                e[(4 * q + 2) * EWS + j] = __expf(-a.z * rv);
                e[(4 * q + 3) * EWS + j] = __expf(-a.w * rv);
            }
            const float4* m4 = (const float4*)(mapping + ((size_t)b * N_ + N1_ + cr0) * N_);
            const float4* s4 = (const float4*)(samelb + ((size_t)b * N_ + N1_ + cr0) * N_);
            // independent mask loads issued before the barrier
            float4 mL = ntl4(&m4[r * 128 + c4]);
            float4 sL = ntl4(&s4[r * 128 + c4]);
            float4 mR[3], sR[3];
            #pragma unroll
            for (int k = 0; k < 3; ++k) {
                int c = c4 + 32 * k;
                mR[k] = ntl4(&m4[r * 128 + 32 + c]);
                sR[k] = ntl4(&s4[r * 128 + 32 + c]);
            }
            __syncthreads();                      // ew[it&1] ready (also fences buf reuse, 2 apart)
            float4 w = *(const float4*)&e[r * EWS + c4 * 4];
            top += mL.x * w.x + mL.y * w.y + mL.z * w.z + mL.w * w.w;
            bot += sL.x * w.x + sL.y * w.y + sL.z * w.z + sL.w * w.w;
            #pragma unroll
            for (int k = 0; k < 3; ++k) {
                top += mR[k].x + mR[k].y + mR[k].z + mR[k].w;
                bot += sR[k].x + sR[k].y + sR[k].z + sR[k].w;
            }
        }
    }
    for (int off = 32; off > 0; off >>= 1) {
        top += __shfl_down(top, off, 64);
        bot += __shfl_down(bot, off, 64);
    }
    int wv = t >> 6, ln = t & 63;
    if (ln == 0) { rt[wv] = top; rb[wv] = bot; }
    __syncthreads();
    if (t == 0) {
        atomicAdd(&ws[ACC_TOP + b], rt[0] + rt[1] + rt[2] + rt[3]);
        atomicAdd(&ws[ACC_BOT + b], rb[0] + rb[1] + rb[2] + rb[3]);
    }
}

// ---------------- back: kabsch+finalize (y==0) | scores MLP (y==1) | pairdst (y==2) ----------
__device__ inline float bred(float* s2, float v, int t) {
    for (int off = 32; off > 0; off >>= 1) v += __shfl_down(v, off, 64);
    if ((t & 63) == 0) s2[t >> 6] = v;
    __syncthreads();
    float r = s2[0] + s2[1];
    __syncthreads();
    return r;
}

// grid (B, 3), block 128
__global__ void k_back(const float* __restrict__ coords, const float* __restrict__ upd,
                       const float* __restrict__ nm, const int* __restrict__ ei,
                       const float* __restrict__ W0, const float* __restrict__ b0,
                       const float* __restrict__ W1, const float* __restrict__ b1,
                       const float* __restrict__ W2, const float* __restrict__ b2,
                       const float* __restrict__ W3, const float* __restrict__ b3,
                       const float* __restrict__ ws, float* __restrict__ out) {
    __shared__ float sh[2 * DFC];
    int b = blockIdx.x, t = threadIdx.x;
    if (blockIdx.y == 2) {
        // ---- pairdst (independent; overlaps Kabsch blocks) ----
        float* s2 = sh;
        const float* C = coords + (size_t)b * N_ * 3;
        const float* U = upd + (size_t)b * N_ * 3;
        const int* e = ei + (size_t)b * E_ * 2;
        float acc = 0.f;
        for (int idx = t; idx < E_; idx += 128) {
            int a0 = e[idx * 2], a1 = e[idx * 2 + 1];
            float ex = C[a0 * 3] - C[a1 * 3], ey = C[a0 * 3 + 1] - C[a1 * 3 + 1], ez = C[a0 * 3 + 2] - C[a1 * 3 + 2];
            float d0 = sqrtf(ex * ex + ey * ey + ez * ez + 1e-12f);
            ex = U[a0 * 3] - U[a1 * 3]; ey = U[a0 * 3 + 1] - U[a1 * 3 + 1]; ez = U[a0 * 3 + 2] - U[a1 * 3 + 2];
            float d1 = sqrtf(ex * ex + ey * ey + ez * ez + 1e-12f);
            acc += d1 - d0;
        }
        float psum = bred(s2, acc, t);
        if (t == 0) atomicAdd(&out[130], fabsf(psum) * (1.f / 128.f));
        return;
    }
    if (blockIdx.y == 1) {
        // ---- scores MLP ----
        float* pool = sh;           // 64
        float* h    = sh + 64;      // 128
        __shared__ float part[DFC];
        if (t < DIN) pool[t] = ws[POOL_OFF + b * DIN + t] * (1.0f / 128.0f);
        __syncthreads();
        float a = b0[t];
        #pragma unroll
        for (int i = 0; i < DIN; ++i) a += pool[i] * W0[i * DFC + t];
        float hv = fmaxf(a, 0.f);
        __syncthreads(); h[t] = hv; __syncthreads();
        a = b1[t];
        #pragma unroll
        for (int i = 0; i < DFC; ++i) a += h[i] * W1[i * DFC + t];
        hv = fmaxf(a, 0.f);
        __syncthreads(); h[t] = hv; __syncthreads();
        a = b2[t];
        #pragma unroll
        for (int i = 0; i < DFC; ++i) a += h[i] * W2[i * DFC + t];
        part[t] = fmaxf(a, 0.f) * W3[t];
        __syncthreads();
        for (int off = 64; off > 0; off >>= 1) { if (t < off) part[t] += part[t + off]; __syncthreads(); }
        if (t == 0) out[b] = 1.f / (1.f + expf(-(part[0] + b3[0])));
        return;
    }
    // ---- Kabsch ----
    float* s2 = sh;
    __shared__ float Rsh[9], Tsh[3];
    int bidx = ((const int*)ws)[BI_OFF + b * N1_ + t];
    float P[3], Q[3];
    const float* up = upd + ((size_t)b * N_ + t) * 3;
    P[0] = up[0]; P[1] = up[1]; P[2] = up[2];
    const float* qp = coords + ((size_t)b * N_ + N1_ + bidx) * 3;
    Q[0] = qp[0]; Q[1] = qp[1]; Q[2] = qp[2];
    float Pm[3], Qm[3];
    for (int a = 0; a < 3; ++a) Pm[a] = bred(s2, P[a], t) * (1.f / 128.f);
    for (int a = 0; a < 3; ++a) Qm[a] = bred(s2, Q[a], t) * (1.f / 128.f);
    float H[9];
    for (int a = 0; a < 3; ++a)
        for (int c = 0; c < 3; ++c)
            H[a * 3 + c] = bred(s2, (P[a] - Pm[a]) * (Q[c] - Qm[c]), t) * (1.f / 8.f);
    if (t == 0) {
        double Hd[3][3];
        for (int a = 0; a < 3; ++a) for (int c = 0; c < 3; ++c) Hd[a][c] = (double)H[a * 3 + c];
        double A[3][3], V[3][3] = {{1,0,0},{0,1,0},{0,0,1}};
        for (int i = 0; i < 3; ++i)
            for (int j = 0; j < 3; ++j) {
                double z = 0; for (int c = 0; c < 3; ++c) z += Hd[c][i] * Hd[c][j];
                A[i][j] = z;
            }
        for (int sweep = 0; sweep < 8; ++sweep) {
            const int PQ[3][2] = {{0,1},{0,2},{1,2}};
            for (int r = 0; r < 3; ++r) {
                int p = PQ[r][0], q = PQ[r][1];
                double apq = A[p][q];
                if (fabs(apq) < 1e-300) continue;
                double tau = (A[q][q] - A[p][p]) / (2.0 * apq);
                double tt = (tau >= 0 ? 1.0 : -1.0) / (fabs(tau) + sqrt(1.0 + tau * tau));
                double c = 1.0 / sqrt(1.0 + tt * tt), s = tt * c;
                for (int k = 0; k < 3; ++k) { double akp = A[k][p], akq = A[k][q]; A[k][p] = c * akp - s * akq; A[k][q] = s * akp + c * akq; }
                for (int k = 0; k < 3; ++k) { double apk = A[p][k], aqk = A[q][k]; A[p][k] = c * apk - s * aqk; A[q][k] = s * apk + c * aqk; }
                for (int k = 0; k < 3; ++k) { double vkp = V[k][p], vkq = V[k][q]; V[k][p] = c * vkp - s * vkq; V[k][q] = s * vkp + c * vkq; }
            }
        }
        double lam[3] = {A[0][0], A[1][1], A[2][2]};
        int id[3] = {0, 1, 2};
        if (lam[id[0]] < lam[id[1]]) { int x = id[0]; id[0] = id[1]; id[1] = x; }
        if (lam[id[0]] < lam[id[2]]) { int x = id[0]; id[0] = id[2]; id[2] = x; }
        if (lam[id[1]] < lam[id[2]]) { int x = id[1]; id[1] = id[2]; id[2] = x; }
        double u[3][3], v[3][3], sv[3];
        for (int i = 0; i < 3; ++i) {
            for (int k = 0; k < 3; ++k) v[i][k] = V[k][id[i]];
            double uv[3];
            for (int c = 0; c < 3; ++c) uv[c] = Hd[c][0] * v[i][0] + Hd[c][1] * v[i][1] + Hd[c][2] * v[i][2];
            double n = sqrt(uv[0] * uv[0] + uv[1] * uv[1] + uv[2] * uv[2]);
            sv[i] = n;
            if (n > 1e-150) { u[i][0] = uv[0] / n; u[i][1] = uv[1] / n; u[i][2] = uv[2] / n; }
            else { u[i][0] = u[i][1] = u[i][2] = 0.0; }
        }
        if (sv[2] < 1e-12 * fmax(sv[0], 1e-300)) {
            u[2][0] = u[0][1] * u[1][2] - u[0][2] * u[1][1];
            u[2][1] = u[0][2] * u[1][0] - u[0][0] * u[1][2];
            u[2][2] = u[0][0] * u[1][1] - u[0][1] * u[1][0];
        }
        double det = Hd[0][0] * (Hd[1][1] * Hd[2][2] - Hd[1][2] * Hd[2][1])
                   - Hd[0][1] * (Hd[1][0] * Hd[2][2] - Hd[1][2] * Hd[2][0])
                   + Hd[0][2] * (Hd[1][0] * Hd[2][1] - Hd[1][1] * Hd[2][0]);
        double dsg = (det > 0.0) ? 1.0 : ((det < 0.0) ? -1.0 : 0.0);
        for (int a = 0; a < 3; ++a)
            for (int c = 0; c < 3; ++c)
                Rsh[a * 3 + c] = (float)(u[0][a] * v[0][c] + u[1][a] * v[1][c] + dsg * u[2][a] * v[2][c]);
        for (int a = 0; a < 3; ++a)
            Tsh[a] = Qm[a] - (Rsh[a * 3] * Pm[0] + Rsh[a * 3 + 1] * Pm[1] + Rsh[a * 3 + 2] * Pm[2]);
    }
    __syncthreads();
    float Pp[3];
    for (int a = 0; a < 3; ++a)
        Pp[a] = Rsh[a * 3] * P[0] + Rsh[a * 3 + 1] * P[1] + Rsh[a * 3 + 2] * P[2] + Tsh[a];
    float mk = (nm[b * N1_ + t] > 0.5f) ? 1.f : 0.f;
    float dx = Pp[0] - Q[0], dy = Pp[1] - Q[1], dz = Pp[2] - Q[2];
    float rsum = bred(s2, mk * (dx * dx + dy * dy + dz * dz), t);
    float msum = bred(s2, mk, t);
    float Ppm[3];
    for (int a = 0; a < 3; ++a) Ppm[a] = bred(s2, Pp[a], t) * (1.f / 128.f);
    if (t == 0) {
        float cnt = fmaxf(msum * 3.f, 1.f);
        atomicAdd(&out[129], (rsum / cnt) * (1.f / 128.f));
        float cen = 0.f;
        for (int a = 0; a < 3; ++a) { float d2 = Ppm[a] - Qm[a]; cen += d2 * d2; }
        atomicAdd(&out[131], (cen / 3.f) * (1.f / 128.f));
    }
    // ---- attn_loss finalize ----
    if (b == 0) {
        float top = ws[ACC_TOP + t], bot = ws[ACC_BOT + t];
        float v = top / (bot - top + 1.0f);
        float s = bred(s2, v, t);
        if (t == 0) out[128] = s * (1.0f / 128.0f);
    }
}

extern "C" void kernel_launch(void* const* d_in, const int* in_sizes, int n_in,
                              void* d_out, int out_size, void* d_ws, size_t ws_size,
                              hipStream_t stream) {
    const float* c_hs      = (const float*)d_in[0];
    const float* attention = (const float*)d_in[1];
    const float* coords    = (const float*)d_in[2];
    const float* upd       = (const float*)d_in[3];
    const float* c_valid   = (const float*)d_in[4];
    const float* nm        = (const float*)d_in[5];
    const float* mapping   = (const float*)d_in[6];
    const float* samelb    = (const float*)d_in[7];
    const int*   ei        = (const int*)d_in[8];
    const float* W0 = (const float*)d_in[9],  *b0 = (const float*)d_in[10];
    const float* W1 = (const float*)d_in[11], *b1 = (const float*)d_in[12];
    const float* W2 = (const float*)d_in[13], *b2 = (const float*)d_in[14];
    const float* W3 = (const float*)d_in[15], *b3 = (const float*)d_in[16];
    float* out = (float*)d_out;
    float* ws  = (float*)d_ws;

    hipLaunchKernelGGL(k_pre,  dim3(B_, 2), dim3(512), 0, stream, c_hs, c_valid, attention, ws, out);
    hipLaunchKernelGGL(k_scan, dim3(2048),  dim3(256), 0, stream, attention, mapping, samelb, ws);
    hipLaunchKernelGGL(k_back, dim3(B_, 3), dim3(128), 0, stream, coords, upd, nm, ei,
                       W0, b0, W1, b1, W2, b2, W3, b3, ws, out);
}